// Round 1
// baseline (1301.591 us; speedup 1.0000x reference)
//
#include <hip/hip_runtime.h>
#include <math.h>

#define BB 4
#define TT 1024
#define CCH 1024
#define HH 16
#define DD 64
#define EE 8
#define HID 128

// ============================================================================
// Kernel A: router (top-2 of 8) + sparse expert MLP (64->128 gelu ->64) + RoPE
// One block = (b, h, 32-token tile). 128 threads.
// Tokens grouped per (proj, expert) so each expert's weights stream once.
// ============================================================================
__global__ __launch_bounds__(128) void moe_qkv_kernel(
    const float* __restrict__ x, const int* __restrict__ pos_ids,
    const float* __restrict__ cosb, const float* __restrict__ sinb,
    const float* __restrict__ rq, const float* __restrict__ rk, const float* __restrict__ rv,
    const float* __restrict__ qw1, const float* __restrict__ qw2,
    const float* __restrict__ kw1, const float* __restrict__ kw2,
    const float* __restrict__ vw1, const float* __restrict__ vw2,
    float* __restrict__ qo, float* __restrict__ ko, float* __restrict__ vo)
{
    const int tid  = threadIdx.x;
    const int blk  = blockIdx.x;
    const int tile = blk & 31;          // T/32 = 32 tiles
    const int h    = (blk >> 5) & 15;
    const int b    = blk >> 9;
    const int t0   = tile * 32;

    __shared__ float xs[32][DD];            // 8 KB  token slice of x
    __shared__ float logits[32][24];        // 3 KB  [tok][p*8+e]
    __shared__ int   sel_e[32][3][2];
    __shared__ float sel_w[32][3][2];
    __shared__ int   cnt[3][EE];
    __shared__ unsigned char lists[3][EE][64];
    __shared__ float hb[8][HID];            // 4 KB  gelu hidden for a token group
    __shared__ float oacc[32][DD];          // 8 KB  per-proj output accumulator

    // ---- load x tile ----
    for (int i = tid; i < 32 * DD; i += 128) {
        int tok = i >> 6, d = i & 63;
        xs[tok][d] = x[((size_t)(b * TT + t0 + tok)) * CCH + h * DD + d];
    }
    if (tid < 24) ((int*)cnt)[tid] = 0;
    __syncthreads();

    // ---- router logits: 32 tok x 3 proj x 8 experts ----
    const float* rW[3] = {rq, rk, rv};
    for (int i = tid; i < 32 * 24; i += 128) {
        int tok = i / 24, rem = i - tok * 24, p = rem >> 3, e = rem & 7;
        const float* r = rW[p];
        float acc = 0.f;
        #pragma unroll 4
        for (int d = 0; d < DD; ++d) acc += xs[tok][d] * r[d * EE + e];
        logits[tok][rem] = acc;
    }
    __syncthreads();

    // ---- top-2 + softmax weights + expert lists ----
    if (tid < 96) {
        int tok = tid / 3, p = tid - tok * 3;
        const float* lg = &logits[tok][p * 8];
        int i1 = 0; float v1 = lg[0];
        #pragma unroll
        for (int e = 1; e < 8; ++e) { if (lg[e] > v1) { v1 = lg[e]; i1 = e; } }
        int i2 = -1; float v2 = -3.402823466e38f;
        #pragma unroll
        for (int e = 0; e < 8; ++e) { if (e != i1 && lg[e] > v2) { v2 = lg[e]; i2 = e; } }
        float z   = expf(v2 - v1);          // v2 <= v1
        float inv = 1.f / (1.f + z);
        sel_e[tok][p][0] = i1; sel_e[tok][p][1] = i2;
        sel_w[tok][p][0] = inv; sel_w[tok][p][1] = z * inv;
        int p0 = atomicAdd(&cnt[p][i1], 1);
        lists[p][i1][p0] = (unsigned char)(tok * 2 + 0);
        int p1 = atomicAdd(&cnt[p][i2], 1);
        lists[p][i2][p1] = (unsigned char)(tok * 2 + 1);
    }
    __syncthreads();

    const float* W1[3] = {qw1, kw1, vw1};
    const float* W2[3] = {qw2, kw2, vw2};
    float* OUT[3] = {qo, ko, vo};

    for (int p = 0; p < 3; ++p) {
        for (int i = tid; i < 32 * DD; i += 128) ((float*)oacc)[i] = 0.f;
        __syncthreads();
        const float* w1base = W1[p];
        const float* w2base = W2[p];

        for (int e = 0; e < EE; ++e) {
            int n = cnt[p][e];
            if (n == 0) continue;
            const float* w1 = w1base + e * DD * HID;
            const float* w2 = w2base + e * HID * DD;

            for (int g0 = 0; g0 < n; g0 += 8) {
                int  gtok[8]; float gwt[8]; bool gval[8];
                #pragma unroll
                for (int i = 0; i < 8; ++i) {
                    int j  = g0 + i;
                    int jc = (j < n) ? j : (n - 1);
                    int li = lists[p][e][jc];
                    int tok = li >> 1, s = li & 1;
                    gtok[i] = tok;
                    gval[i] = (j < n);
                    gwt[i]  = sel_w[tok][p][s];
                }
                // phase 1: hidden = gelu(x @ w1), thread = f in [0,128)
                float acc[8] = {0, 0, 0, 0, 0, 0, 0, 0};
                #pragma unroll 4
                for (int d = 0; d < DD; ++d) {
                    float wv = w1[d * HID + tid];
                    #pragma unroll
                    for (int i = 0; i < 8; ++i) acc[i] += wv * xs[gtok[i]][d];
                }
                #pragma unroll
                for (int i = 0; i < 8; ++i) {
                    float zv = acc[i];
                    // gelu(z) = z * sigmoid(2c(z + 0.044715 z^3)), c = sqrt(2/pi)
                    float u = 1.5957691216057308f * (zv + 0.044715f * zv * zv * zv);
                    hb[i][tid] = zv / (1.f + __expf(-u));
                }
                __syncthreads();
                // phase 2: out = hidden @ w2, threads split: half per 4 tokens
                {
                    int g = tid & 63;
                    int halfsel = tid >> 6;
                    float acc2[4] = {0, 0, 0, 0};
                    const float* hbp = &hb[halfsel * 4][0];
                    #pragma unroll 4
                    for (int f = 0; f < HID; ++f) {
                        float wv = w2[f * DD + g];
                        #pragma unroll
                        for (int i = 0; i < 4; ++i) acc2[i] += wv * hbp[i * HID + f];
                    }
                    #pragma unroll
                    for (int i = 0; i < 4; ++i) {
                        int ii = halfsel * 4 + i;
                        if (gval[ii]) oacc[gtok[ii]][g] += gwt[ii] * acc2[i];
                    }
                }
                __syncthreads();
            }
        }

        // ---- RoPE (p<2) + store to [B,H,T,D] ----
        float* outp = OUT[p];
        for (int i = tid; i < 32 * DD; i += 128) {
            int tok = i >> 6, d = i & 63;
            int tg  = t0 + tok;
            float val = oacc[tok][d];
            float res;
            if (p < 2) {
                int pos  = pos_ids[b * TT + tg];
                float cv = cosb[pos * DD + d];
                float sv = sinb[pos * DD + d];
                float rot = (d < 32) ? -oacc[tok][d + 32] : oacc[tok][d - 32];
                res = val * cv + rot * sv;
            } else {
                res = val;
            }
            outp[(((size_t)(b * HH + h)) * TT + tg) * DD + d] = res;
        }
        __syncthreads();
    }
}

// ============================================================================
// Kernel B: causal flash attention, fp32. Block = (b, h, 64-q-tile), 256 thr.
// Transposed LDS layouts so inner loops use 16B LDS reads.
// ============================================================================
__global__ __launch_bounds__(256) void attn_kernel(
    const float* __restrict__ q, const float* __restrict__ k,
    const float* __restrict__ v, float* __restrict__ out)
{
    const int tid  = threadIdx.x;
    const int blk  = blockIdx.x;
    const int tile = blk & 15;          // T/64 = 16
    const int h    = (blk >> 4) & 15;
    const int b    = blk >> 8;
    const int q0   = tile * 64;
    const size_t plane = ((size_t)(b * HH + h)) * TT * DD;
    const float* qp = q + plane;
    const float* kp = k + plane;
    const float* vp = v + plane;

    __shared__ __align__(16) float Qt[DD][68];   // [d][qi]
    __shared__ __align__(16) float Kt[DD][68];   // [d][kj]
    __shared__ __align__(16) float Vs[64][68];   // [kj][d]
    __shared__ __align__(16) float Pt[64][68];   // [kj][qi]
    __shared__ float mrow[64], lrow[64], arow[64];

    const int tx = tid & 15, ty = tid >> 4;

    for (int i = tid; i < 64 * DD; i += 256) {
        int r = i >> 6, d = i & 63;
        Qt[d][r] = qp[(size_t)(q0 + r) * DD + d];
    }
    if (tid < 64) { mrow[tid] = -3.402823466e38f; lrow[tid] = 0.f; }
    float o[4][4];
    #pragma unroll
    for (int i = 0; i < 4; ++i)
        #pragma unroll
        for (int j = 0; j < 4; ++j) o[i][j] = 0.f;
    __syncthreads();

    const int ntiles = tile + 1;
    for (int kt = 0; kt < ntiles; ++kt) {
        const int k0 = kt * 64;
        for (int i = tid; i < 64 * DD; i += 256) {
            int r = i >> 6, d = i & 63;
            Kt[d][r] = kp[(size_t)(k0 + r) * DD + d];
            Vs[r][d] = vp[(size_t)(k0 + r) * DD + d];
        }
        __syncthreads();

        // S = (Q K^T) / 8  (4x4 micro-tile)
        float acc[4][4];
        #pragma unroll
        for (int i = 0; i < 4; ++i)
            #pragma unroll
            for (int j = 0; j < 4; ++j) acc[i][j] = 0.f;
        #pragma unroll 4
        for (int d = 0; d < DD; ++d) {
            float4 a4 = *(const float4*)&Qt[d][4 * ty];
            float4 b4 = *(const float4*)&Kt[d][4 * tx];
            const float av[4] = {a4.x, a4.y, a4.z, a4.w};
            const float bv[4] = {b4.x, b4.y, b4.z, b4.w};
            #pragma unroll
            for (int i = 0; i < 4; ++i)
                #pragma unroll
                for (int j = 0; j < 4; ++j) acc[i][j] += av[i] * bv[j];
        }
        // masked, scaled, transposed into Pt
        #pragma unroll
        for (int i = 0; i < 4; ++i) {
            #pragma unroll
            for (int j = 0; j < 4; ++j) {
                int qg = q0 + 4 * ty + i, kg = k0 + 4 * tx + j;
                Pt[4 * tx + j][4 * ty + i] =
                    (kg <= qg) ? acc[i][j] * 0.125f : -3.402823466e38f;
            }
        }
        __syncthreads();

        // online-softmax row pass (one thread per q row)
        if (tid < 64) {
            int r = tid;
            float mold = mrow[r];
            float rm = -3.402823466e38f;
            for (int j = 0; j < 64; ++j) rm = fmaxf(rm, Pt[j][r]);
            float mn = fmaxf(mold, rm);
            float al = __expf(mold - mn);
            float s  = 0.f;
            for (int j = 0; j < 64; ++j) {
                float pv = __expf(Pt[j][r] - mn);
                Pt[j][r] = pv;
                s += pv;
            }
            mrow[r] = mn;
            lrow[r] = lrow[r] * al + s;
            arow[r] = al;
        }
        __syncthreads();

        // rescale O and accumulate P @ V
        float al[4];
        #pragma unroll
        for (int i = 0; i < 4; ++i) al[i] = arow[4 * ty + i];
        #pragma unroll
        for (int i = 0; i < 4; ++i)
            #pragma unroll
            for (int j = 0; j < 4; ++j) o[i][j] *= al[i];
        #pragma unroll 4
        for (int j = 0; j < 64; ++j) {
            float4 p4 = *(const float4*)&Pt[j][4 * ty];
            float4 v4 = *(const float4*)&Vs[j][4 * tx];
            const float pv[4] = {p4.x, p4.y, p4.z, p4.w};
            const float vv[4] = {v4.x, v4.y, v4.z, v4.w};
            #pragma unroll
            for (int i = 0; i < 4; ++i)
                #pragma unroll
                for (int jj = 0; jj < 4; ++jj) o[i][jj] += pv[i] * vv[jj];
        }
        __syncthreads();
    }

    // epilogue: normalize, store to [B,T,C] (head-interleaved)
    #pragma unroll
    for (int i = 0; i < 4; ++i) {
        float linv = 1.f / lrow[4 * ty + i];
        float4 st;
        st.x = o[i][0] * linv; st.y = o[i][1] * linv;
        st.z = o[i][2] * linv; st.w = o[i][3] * linv;
        *(float4*)&out[((size_t)(b * TT + q0 + 4 * ty + i)) * CCH + h * DD + 4 * tx] = st;
    }
}

// ============================================================================
// Kernel C: output projection  C[m,n] = sum_k A[m,k] * W[n,k]
// 64x64 tile / block, 256 threads, 4x4 micro-tile.
// ============================================================================
__global__ __launch_bounds__(256) void oproj_kernel(
    const float* __restrict__ A, const float* __restrict__ W,
    float* __restrict__ Cout)
{
    const int tid = threadIdx.x;
    const int bn  = blockIdx.x & 15;    // 1024/64 = 16 n-tiles
    const int bm  = blockIdx.x >> 4;    // 4096/64 = 64 m-tiles
    const int m0 = bm * 64, n0 = bn * 64;
    const int tx = tid & 15, ty = tid >> 4;

    __shared__ __align__(16) float As[16][68];   // [kk][m]
    __shared__ __align__(16) float Bs[16][68];   // [kk][n]

    float acc[4][4];
    #pragma unroll
    for (int i = 0; i < 4; ++i)
        #pragma unroll
        for (int j = 0; j < 4; ++j) acc[i][j] = 0.f;

    for (int k0 = 0; k0 < 1024; k0 += 16) {
        for (int i = tid; i < 1024; i += 256) {
            int r = i >> 4, kk = i & 15;
            As[kk][r] = A[(size_t)(m0 + r) * 1024 + k0 + kk];
            Bs[kk][r] = W[(size_t)(n0 + r) * 1024 + k0 + kk];
        }
        __syncthreads();
        #pragma unroll
        for (int kk = 0; kk < 16; ++kk) {
            float4 a4 = *(const float4*)&As[kk][4 * ty];
            float4 b4 = *(const float4*)&Bs[kk][4 * tx];
            const float av[4] = {a4.x, a4.y, a4.z, a4.w};
            const float bv[4] = {b4.x, b4.y, b4.z, b4.w};
            #pragma unroll
            for (int i = 0; i < 4; ++i)
                #pragma unroll
                for (int j = 0; j < 4; ++j) acc[i][j] += av[i] * bv[j];
        }
        __syncthreads();
    }
    #pragma unroll
    for (int i = 0; i < 4; ++i) {
        float4 st;
        st.x = acc[i][0]; st.y = acc[i][1]; st.z = acc[i][2]; st.w = acc[i][3];
        *(float4*)&Cout[(size_t)(m0 + 4 * ty + i) * 1024 + n0 + 4 * tx] = st;
    }
}

// ============================================================================
extern "C" void kernel_launch(void* const* d_in, const int* in_sizes, int n_in,
                              void* d_out, int out_size, void* d_ws, size_t ws_size,
                              hipStream_t stream) {
    (void)in_sizes; (void)n_in; (void)out_size; (void)ws_size;
    const float* x    = (const float*)d_in[0];
    const int*   pid  = (const int*)  d_in[1];
    const float* cosb = (const float*)d_in[2];
    const float* sinb = (const float*)d_in[3];
    const float* rq   = (const float*)d_in[4];
    const float* rk   = (const float*)d_in[5];
    const float* rv   = (const float*)d_in[6];
    const float* qw1  = (const float*)d_in[7];
    const float* qw2  = (const float*)d_in[8];
    const float* kw1  = (const float*)d_in[9];
    const float* kw2  = (const float*)d_in[10];
    const float* vw1  = (const float*)d_in[11];
    const float* vw2  = (const float*)d_in[12];
    const float* ow   = (const float*)d_in[13];
    float* out = (float*)d_out;

    float* ws = (float*)d_ws;
    const size_t PLANE = (size_t)BB * HH * TT * DD;   // 4194304 floats
    float* qb = ws;
    float* kb = ws + PLANE;
    float* vb = ws + 2 * PLANE;
    float* ao = ws + 3 * PLANE;                       // [B,T,C] = 4194304 floats

    hipLaunchKernelGGL(moe_qkv_kernel, dim3(2048), dim3(128), 0, stream,
                       x, pid, cosb, sinb, rq, rk, rv,
                       qw1, qw2, kw1, kw2, vw1, vw2, qb, kb, vb);
    hipLaunchKernelGGL(attn_kernel, dim3(1024), dim3(256), 0, stream,
                       qb, kb, vb, ao);
    hipLaunchKernelGGL(oproj_kernel, dim3(1024), dim3(256), 0, stream,
                       ao, ow, out);
}

// Round 2
// 1039.448 us; speedup vs baseline: 1.2522x; 1.2522x over previous
//
#include <hip/hip_runtime.h>
#include <math.h>

#define BB 4
#define TT 1024
#define CCH 1024
#define HH 16
#define DD 64
#define EE 8
#define HID 128
#define CAP 24576   // entries per (proj,expert) list; mean is 16384

typedef unsigned short u16;
typedef short bf16x8 __attribute__((ext_vector_type(8)));
typedef float f32x4 __attribute__((ext_vector_type(4)));

__device__ __forceinline__ u16 f2bf(float f) {
    unsigned int u = __float_as_uint(f);
    unsigned int r = (u + 0x7FFFu + ((u >> 16) & 1u)) >> 16;   // RNE
    return (u16)r;
}

// ============================================================================
// Kernel 1: router. One thread per (b,t,h) "token-head" g; fp32-exact top-2.
// Block-local LDS counting -> 24 global atomics per block -> entry writes.
// g = (b*T + t)*16 + h, so x row base = x + g*64.
// ============================================================================
__global__ __launch_bounds__(256) void router_kernel(
    const float* __restrict__ x,
    const float* __restrict__ rq, const float* __restrict__ rk, const float* __restrict__ rv,
    unsigned int* __restrict__ counts,
    unsigned int* __restrict__ idxbuf, float* __restrict__ wtbuf)
{
    const int tid = threadIdx.x;
    const unsigned int g = blockIdx.x * 256 + tid;

    __shared__ float rS[3][64][8];
    __shared__ int lcnt[24];
    __shared__ int lbase[24];

    for (int i = tid; i < 1536; i += 256) {
        int p = i >> 9, rem = i & 511;
        const float* rp = (p == 0) ? rq : (p == 1) ? rk : rv;
        rS[p][rem >> 3][rem & 7] = rp[rem];
    }
    if (tid < 24) lcnt[tid] = 0;
    __syncthreads();

    float lg[3][8];
    #pragma unroll
    for (int p = 0; p < 3; ++p)
        #pragma unroll
        for (int e = 0; e < 8; ++e) lg[p][e] = 0.f;

    const float* xr = x + (size_t)g * 64;
    for (int i4 = 0; i4 < 16; ++i4) {
        float4 xv = ((const float4*)xr)[i4];
        float xa[4] = {xv.x, xv.y, xv.z, xv.w};
        #pragma unroll
        for (int m = 0; m < 4; ++m) {
            int d = i4 * 4 + m;
            #pragma unroll
            for (int p = 0; p < 3; ++p) {
                float4 r0 = *(const float4*)&rS[p][d][0];
                float4 r1 = *(const float4*)&rS[p][d][4];
                lg[p][0] += xa[m] * r0.x; lg[p][1] += xa[m] * r0.y;
                lg[p][2] += xa[m] * r0.z; lg[p][3] += xa[m] * r0.w;
                lg[p][4] += xa[m] * r1.x; lg[p][5] += xa[m] * r1.y;
                lg[p][6] += xa[m] * r1.z; lg[p][7] += xa[m] * r1.w;
            }
        }
    }

    int se[3][2]; float sw[3][2]; int slot[3][2];
    #pragma unroll
    for (int p = 0; p < 3; ++p) {
        int i1 = 0; float v1 = lg[p][0];
        #pragma unroll
        for (int e = 1; e < 8; ++e) { if (lg[p][e] > v1) { v1 = lg[p][e]; i1 = e; } }
        int i2 = -1; float v2 = -3.402823466e38f;
        #pragma unroll
        for (int e = 0; e < 8; ++e) { if (e != i1 && lg[p][e] > v2) { v2 = lg[p][e]; i2 = e; } }
        float z = __expf(v2 - v1);
        float inv = 1.f / (1.f + z);
        se[p][0] = i1; se[p][1] = i2;
        sw[p][0] = inv; sw[p][1] = z * inv;
        slot[p][0] = atomicAdd(&lcnt[p * 8 + i1], 1);
        slot[p][1] = atomicAdd(&lcnt[p * 8 + i2], 1);
    }
    __syncthreads();
    if (tid < 24) lbase[tid] = (int)atomicAdd(&counts[tid], (unsigned int)lcnt[tid]);
    __syncthreads();
    #pragma unroll
    for (int p = 0; p < 3; ++p)
        #pragma unroll
        for (int s = 0; s < 2; ++s) {
            int pe = p * 8 + se[p][s];
            int pos = lbase[pe] + slot[p][s];
            if (pos < CAP) {
                idxbuf[pe * CAP + pos] = g;
                wtbuf[pe * CAP + pos]  = sw[p][s];
            }
        }
}

// ============================================================================
// Kernel 2: grouped expert MLP, fp32. Grid = 24 (p,e) x 48 chunks.
// Each block: 64-token tiles (grid-strided), gather x -> LDS, two GEMM
// phases with 32/16-FMA micro-tiles, weighted fp32 atomicAdd scatter.
// ============================================================================
__global__ __launch_bounds__(256) void expert_kernel(
    const float* __restrict__ x,
    const float* __restrict__ w1q, const float* __restrict__ w2q,
    const float* __restrict__ w1k, const float* __restrict__ w2k,
    const float* __restrict__ w1v, const float* __restrict__ w2v,
    const unsigned int* __restrict__ counts,
    const unsigned int* __restrict__ idxbuf, const float* __restrict__ wtbuf,
    float* __restrict__ qf, float* __restrict__ kf, float* __restrict__ vf)
{
    const int tid = threadIdx.x;
    const int CH = 48;
    int pe = blockIdx.x / CH;
    int chunk = blockIdx.x - pe * CH;
    int p = pe >> 3, e = pe & 7;
    int n = (int)counts[pe]; if (n > CAP) n = CAP;
    if (n == 0) return;

    const float* w1 = ((p == 0) ? w1q : (p == 1) ? w1k : w1v) + e * 64 * 128;
    const float* w2 = ((p == 0) ? w2q : (p == 1) ? w2k : w2v) + e * 128 * 64;
    float* outp = (p == 0) ? qf : (p == 1) ? kf : vf;
    const unsigned int* il = idxbuf + pe * CAP;
    const float* wl = wtbuf + pe * CAP;

    __shared__ float xs[64][68];       // 17.4 KB, stride 68: aligned + low-conflict
    __shared__ float hb[64][132];      // 33.8 KB gelu hidden
    __shared__ unsigned int stoks[64];
    __shared__ unsigned int sobase[64];
    __shared__ float swt[64];

    int tiles = (n + 63) >> 6;
    for (int t = chunk; t < tiles; t += CH) {
        int base = t * 64;
        __syncthreads();
        if (tid < 64) {
            int j = base + tid;
            int jc = (j < n) ? j : (n - 1);
            unsigned int g = il[jc];
            stoks[tid] = g;
            swt[tid] = (j < n) ? wl[jc] : 0.f;
            unsigned int b_ = g >> 14, h_ = g & 15, t_ = (g >> 4) & 1023;
            sobase[tid] = ((b_ * 16 + h_) * 1024 + t_) * 64;
        }
        __syncthreads();
        // gather x tile (coalesced float4)
        {
            int row = tid >> 2, cg = tid & 3;
            const float* xr = x + (size_t)stoks[row] * 64 + cg * 16;
            float4 v0 = ((const float4*)xr)[0];
            float4 v1 = ((const float4*)xr)[1];
            float4 v2 = ((const float4*)xr)[2];
            float4 v3 = ((const float4*)xr)[3];
            float* dst = &xs[row][cg * 16];
            ((float4*)dst)[0] = v0; ((float4*)dst)[1] = v1;
            ((float4*)dst)[2] = v2; ((float4*)dst)[3] = v3;
        }
        __syncthreads();
        // phase 1: hidden = gelu(x @ w1). thread = (f-octet, 4-token group)
        {
            int f0 = (tid & 15) * 8, tg = tid >> 4;
            float acc[4][8];
            #pragma unroll
            for (int i = 0; i < 4; ++i)
                #pragma unroll
                for (int j = 0; j < 8; ++j) acc[i][j] = 0.f;
            #pragma unroll 4
            for (int d = 0; d < 64; ++d) {
                float4 wa = *(const float4*)&w1[d * 128 + f0];
                float4 wb = *(const float4*)&w1[d * 128 + f0 + 4];
                float wv[8] = {wa.x, wa.y, wa.z, wa.w, wb.x, wb.y, wb.z, wb.w};
                float xv[4];
                #pragma unroll
                for (int i = 0; i < 4; ++i) xv[i] = xs[4 * tg + i][d];
                #pragma unroll
                for (int i = 0; i < 4; ++i)
                    #pragma unroll
                    for (int j = 0; j < 8; ++j) acc[i][j] += xv[i] * wv[j];
            }
            #pragma unroll
            for (int i = 0; i < 4; ++i) {
                float tmp[8];
                #pragma unroll
                for (int j = 0; j < 8; ++j) {
                    float z = acc[i][j];
                    float u = 1.5957691216057308f * (z + 0.044715f * z * z * z);
                    tmp[j] = z / (1.f + __expf(-u));   // == 0.5z(1+tanh(...))
                }
                *(float4*)&hb[4 * tg + i][f0]     = make_float4(tmp[0], tmp[1], tmp[2], tmp[3]);
                *(float4*)&hb[4 * tg + i][f0 + 4] = make_float4(tmp[4], tmp[5], tmp[6], tmp[7]);
            }
        }
        __syncthreads();
        // phase 2: out = hidden @ w2. thread = (g-octet, 2-token group)
        {
            int g0 = (tid & 7) * 8, th = tid >> 3;
            float acc[2][8];
            #pragma unroll
            for (int i = 0; i < 2; ++i)
                #pragma unroll
                for (int j = 0; j < 8; ++j) acc[i][j] = 0.f;
            #pragma unroll 4
            for (int f = 0; f < 128; ++f) {
                float4 wa = *(const float4*)&w2[f * 64 + g0];
                float4 wb = *(const float4*)&w2[f * 64 + g0 + 4];
                float wv[8] = {wa.x, wa.y, wa.z, wa.w, wb.x, wb.y, wb.z, wb.w};
                float h0 = hb[2 * th][f], h1 = hb[2 * th + 1][f];
                #pragma unroll
                for (int j = 0; j < 8; ++j) {
                    acc[0][j] += h0 * wv[j];
                    acc[1][j] += h1 * wv[j];
                }
            }
            #pragma unroll
            for (int i = 0; i < 2; ++i) {
                int tok = 2 * th + i;
                float w = swt[tok];
                float* op = outp + sobase[tok] + g0;
                #pragma unroll
                for (int j = 0; j < 8; ++j) atomicAdd(&op[j], w * acc[i][j]);
            }
        }
    }
}

// ============================================================================
// Kernel 3: in-place RoPE on q,k (fp32). cos/sin halves are identical.
// ============================================================================
__global__ __launch_bounds__(256) void rope_kernel(
    float* __restrict__ qf, float* __restrict__ kf,
    const int* __restrict__ pos_ids,
    const float* __restrict__ cosb, const float* __restrict__ sinb)
{
    unsigned int gg = blockIdx.x * 256 + threadIdx.x;   // 0 .. 4M-1
    float* buf = (gg >= (1u << 21)) ? kf : qf;
    unsigned int r = gg & ((1u << 21) - 1);             // B*H*T*32
    int d = r & 31;
    int t = (r >> 5) & 1023;
    int h = (r >> 15) & 15;
    int b = r >> 19;
    int pos = pos_ids[b * 1024 + t];
    float cv = cosb[pos * 64 + d], sv = sinb[pos * 64 + d];
    size_t off = (((size_t)(b * 16 + h)) * 1024 + t) * 64 + d;
    float a = buf[off], bb = buf[off + 32];
    buf[off]      = a * cv - bb * sv;
    buf[off + 32] = bb * cv + a * sv;
}

// ============================================================================
// Kernel 4: fp32 -> bf16 convert (for o_w)
// ============================================================================
__global__ __launch_bounds__(256) void cvt_bf16_kernel(
    const float* __restrict__ in, u16* __restrict__ out, int n4)
{
    int i = blockIdx.x * 256 + threadIdx.x;
    if (i >= n4) return;
    float4 v = ((const float4*)in)[i];
    u16 o[4] = {f2bf(v.x), f2bf(v.y), f2bf(v.z), f2bf(v.w)};
    unsigned int lo = (unsigned int)o[0] | ((unsigned int)o[1] << 16);
    unsigned int hi = (unsigned int)o[2] | ((unsigned int)o[3] << 16);
    ((uint2*)out)[i] = make_uint2(lo, hi);
}

// ============================================================================
// Kernel 5: flash attention, bf16 MFMA 16x16x32, fp32 softmax/accum.
// Block = (b,h,64-row q-tile), 4 waves; wave w owns q rows [16w,16w+16).
// Online softmax fully in-register via shfl_xor(width 16).
// P -> A-layout via per-wave private LDS (no barrier needed).
// ============================================================================
__global__ __launch_bounds__(256) void attn_kernel(
    const float* __restrict__ qf, const float* __restrict__ kf,
    const float* __restrict__ vf, u16* __restrict__ ao)
{
    const int tid = threadIdx.x;
    const int qt = blockIdx.x & 15, h = (blockIdx.x >> 4) & 15, b = blockIdx.x >> 8;
    const int q0 = qt * 64;
    const size_t plane = ((size_t)(b * 16 + h)) * 1024 * 64;
    const float* qp = qf + plane;
    const float* kp = kf + plane;
    const float* vp = vf + plane;

    const int w = tid >> 6, lane = tid & 63, quad = lane >> 4, m16 = lane & 15;

    __shared__ u16 Qs[64][72];        // stride 72 keeps every row 16B-aligned
    __shared__ u16 Ks[64][72];
    __shared__ u16 Vt[64][72];        // [d][kj]
    __shared__ u16 Ps[4][16][72];     // per-wave P scratch

    // stage Q (once)
    {
        int row = tid >> 2, cg = tid & 3;
        const float* src = qp + (size_t)(q0 + row) * 64 + cg * 16;
        u16* dst = &Qs[row][cg * 16];
        #pragma unroll
        for (int c = 0; c < 4; ++c) {
            float4 v = ((const float4*)src)[c];
            dst[c * 4 + 0] = f2bf(v.x); dst[c * 4 + 1] = f2bf(v.y);
            dst[c * 4 + 2] = f2bf(v.z); dst[c * 4 + 3] = f2bf(v.w);
        }
    }
    float m_r[4], l_r[4];
    #pragma unroll
    for (int i = 0; i < 4; ++i) { m_r[i] = -1e30f; l_r[i] = 0.f; }
    f32x4 oacc[4];
    #pragma unroll
    for (int i = 0; i < 4; ++i) oacc[i] = (f32x4){0.f, 0.f, 0.f, 0.f};

    for (int kt = 0; kt <= qt; ++kt) {
        const int k0 = kt * 64;
        __syncthreads();
        // stage K rows
        {
            int row = tid >> 2, cg = tid & 3;
            const float* src = kp + (size_t)(k0 + row) * 64 + cg * 16;
            u16* dst = &Ks[row][cg * 16];
            #pragma unroll
            for (int c = 0; c < 4; ++c) {
                float4 v = ((const float4*)src)[c];
                dst[c * 4 + 0] = f2bf(v.x); dst[c * 4 + 1] = f2bf(v.y);
                dst[c * 4 + 2] = f2bf(v.z); dst[c * 4 + 3] = f2bf(v.w);
            }
        }
        // stage V transposed; d0 is wave-uniform -> conflict-free column writes
        {
            int kj = tid & 63, dg = tid >> 6;
            #pragma unroll
            for (int pp = 0; pp < 4; ++pp) {
                int d0 = dg * 4 + pp * 16;
                float4 v = *(const float4*)&vp[(size_t)(k0 + kj) * 64 + d0];
                Vt[d0 + 0][kj] = f2bf(v.x); Vt[d0 + 1][kj] = f2bf(v.y);
                Vt[d0 + 2][kj] = f2bf(v.z); Vt[d0 + 3][kj] = f2bf(v.w);
            }
        }
        __syncthreads();

        // S = Q K^T  (A-frag: row m16 of wave tile, k = 8*quad+j)
        bf16x8 aq0 = *(const bf16x8*)&Qs[16 * w + m16][8 * quad];
        bf16x8 aq1 = *(const bf16x8*)&Qs[16 * w + m16][32 + 8 * quad];
        f32x4 sv[4];
        #pragma unroll
        for (int ct = 0; ct < 4; ++ct) {
            bf16x8 bk0 = *(const bf16x8*)&Ks[16 * ct + m16][8 * quad];
            bf16x8 bk1 = *(const bf16x8*)&Ks[16 * ct + m16][32 + 8 * quad];
            f32x4 acc = (f32x4){0.f, 0.f, 0.f, 0.f};
            acc = __builtin_amdgcn_mfma_f32_16x16x32_bf16(aq0, bk0, acc, 0, 0, 0);
            acc = __builtin_amdgcn_mfma_f32_16x16x32_bf16(aq1, bk1, acc, 0, 0, 0);
            sv[ct] = acc;
        }

        // scale + causal mask (C layout: row = 4*quad+reg, col = 16*ct+m16)
        float s[4][4];
        const bool diag = (kt == qt);
        #pragma unroll
        for (int ct = 0; ct < 4; ++ct)
            #pragma unroll
            for (int reg = 0; reg < 4; ++reg) {
                float v = sv[ct][reg] * 0.125f;
                if (diag) {
                    int col = 16 * ct + m16;
                    int row = 16 * w + 4 * quad + reg;
                    if (col > row) v = -1e30f;
                }
                s[ct][reg] = v;
            }

        // online softmax, in-register (cols of a row live in 16 contiguous lanes)
        float nm[4], al[4];
        #pragma unroll
        for (int reg = 0; reg < 4; ++reg) {
            float rm = fmaxf(fmaxf(s[0][reg], s[1][reg]), fmaxf(s[2][reg], s[3][reg]));
            #pragma unroll
            for (int off = 1; off < 16; off <<= 1) rm = fmaxf(rm, __shfl_xor(rm, off, 16));
            float mn = fmaxf(m_r[reg], rm);
            nm[reg] = mn;
            al[reg] = __expf(m_r[reg] - mn);
        }
        #pragma unroll
        for (int reg = 0; reg < 4; ++reg) {
            float sum = 0.f;
            #pragma unroll
            for (int ct = 0; ct < 4; ++ct) {
                float pv = __expf(s[ct][reg] - nm[reg]);
                s[ct][reg] = pv;
                sum += pv;
            }
            #pragma unroll
            for (int off = 1; off < 16; off <<= 1) sum += __shfl_xor(sum, off, 16);
            l_r[reg] = l_r[reg] * al[reg] + sum;
            m_r[reg] = nm[reg];
        }

        // P: C-layout -> A-layout via per-wave LDS (in-wave DS ordering, no barrier)
        #pragma unroll
        for (int ct = 0; ct < 4; ++ct)
            #pragma unroll
            for (int reg = 0; reg < 4; ++reg)
                Ps[w][4 * quad + reg][16 * ct + m16] = f2bf(s[ct][reg]);

        #pragma unroll
        for (int dt = 0; dt < 4; ++dt)
            #pragma unroll
            for (int reg = 0; reg < 4; ++reg) oacc[dt][reg] *= al[reg];

        bf16x8 ap0 = *(const bf16x8*)&Ps[w][m16][8 * quad];
        bf16x8 ap1 = *(const bf16x8*)&Ps[w][m16][32 + 8 * quad];
        #pragma unroll
        for (int dt = 0; dt < 4; ++dt) {
            bf16x8 bv0 = *(const bf16x8*)&Vt[16 * dt + m16][8 * quad];
            bf16x8 bv1 = *(const bf16x8*)&Vt[16 * dt + m16][32 + 8 * quad];
            oacc[dt] = __builtin_amdgcn_mfma_f32_16x16x32_bf16(ap0, bv0, oacc[dt], 0, 0, 0);
            oacc[dt] = __builtin_amdgcn_mfma_f32_16x16x32_bf16(ap1, bv1, oacc[dt], 0, 0, 0);
        }
    }

    // epilogue: normalize, store bf16 to [B,T,C]
    #pragma unroll
    for (int reg = 0; reg < 4; ++reg) {
        float linv = 1.f / l_r[reg];
        int row = q0 + 16 * w + 4 * quad + reg;
        size_t base = ((size_t)(b * 1024) + row) * 1024 + h * 64;
        #pragma unroll
        for (int dt = 0; dt < 4; ++dt)
            ao[base + 16 * dt + m16] = f2bf(oacc[dt][reg] * linv);
    }
}

// ============================================================================
// Kernel 6: output projection, bf16 MFMA gemm_bt. out[m][n] = sum_k A[m,k]W[n,k]
// 128x128 tile, BK=32, 4 waves (2x2), each 64x64.
// ============================================================================
__global__ __launch_bounds__(256) void oproj_kernel(
    const u16* __restrict__ A, const u16* __restrict__ Bw,
    float* __restrict__ out)
{
    const int tid = threadIdx.x;
    const int bn = blockIdx.x & 7;     // 1024/128
    const int bm = blockIdx.x >> 3;    // 4096/128
    const int m0 = bm * 128, n0 = bn * 128;
    const int w = tid >> 6, lane = tid & 63, quad = lane >> 4, m16 = lane & 15;
    const int wm = (w >> 1) * 64, wn = (w & 1) * 64;

    __shared__ u16 As[128][32];
    __shared__ u16 Bs[128][32];

    f32x4 acc[4][4];
    #pragma unroll
    for (int mt = 0; mt < 4; ++mt)
        #pragma unroll
        for (int nt = 0; nt < 4; ++nt) acc[mt][nt] = (f32x4){0.f, 0.f, 0.f, 0.f};

    for (int k0 = 0; k0 < 1024; k0 += 32) {
        __syncthreads();
        {
            int row = tid >> 1, sg = (tid & 1) * 16;
            const uint4* srcA = (const uint4*)&A[(size_t)(m0 + row) * 1024 + k0 + sg];
            uint4 a0 = srcA[0], a1 = srcA[1];
            uint4* dstA = (uint4*)&As[row][sg];
            dstA[0] = a0; dstA[1] = a1;
            const uint4* srcB = (const uint4*)&Bw[(size_t)(n0 + row) * 1024 + k0 + sg];
            uint4 b0 = srcB[0], b1 = srcB[1];
            uint4* dstB = (uint4*)&Bs[row][sg];
            dstB[0] = b0; dstB[1] = b1;
        }
        __syncthreads();
        bf16x8 af[4], bf_[4];
        #pragma unroll
        for (int mt = 0; mt < 4; ++mt) af[mt] = *(const bf16x8*)&As[wm + 16 * mt + m16][8 * quad];
        #pragma unroll
        for (int nt = 0; nt < 4; ++nt) bf_[nt] = *(const bf16x8*)&Bs[wn + 16 * nt + m16][8 * quad];
        #pragma unroll
        for (int mt = 0; mt < 4; ++mt)
            #pragma unroll
            for (int nt = 0; nt < 4; ++nt)
                acc[mt][nt] = __builtin_amdgcn_mfma_f32_16x16x32_bf16(af[mt], bf_[nt], acc[mt][nt], 0, 0, 0);
    }
    #pragma unroll
    for (int mt = 0; mt < 4; ++mt)
        #pragma unroll
        for (int nt = 0; nt < 4; ++nt)
            #pragma unroll
            for (int reg = 0; reg < 4; ++reg)
                out[(size_t)(m0 + wm + 16 * mt + 4 * quad + reg) * 1024 + n0 + wn + 16 * nt + m16] =
                    acc[mt][nt][reg];
}

// ============================================================================
extern "C" void kernel_launch(void* const* d_in, const int* in_sizes, int n_in,
                              void* d_out, int out_size, void* d_ws, size_t ws_size,
                              hipStream_t stream) {
    (void)in_sizes; (void)n_in; (void)out_size; (void)ws_size;
    const float* x    = (const float*)d_in[0];
    const int*   pid  = (const int*)  d_in[1];
    const float* cosb = (const float*)d_in[2];
    const float* sinb = (const float*)d_in[3];
    const float* rq   = (const float*)d_in[4];
    const float* rk   = (const float*)d_in[5];
    const float* rv   = (const float*)d_in[6];
    const float* qw1  = (const float*)d_in[7];
    const float* qw2  = (const float*)d_in[8];
    const float* kw1  = (const float*)d_in[9];
    const float* kw2  = (const float*)d_in[10];
    const float* vw1  = (const float*)d_in[11];
    const float* vw2  = (const float*)d_in[12];
    const float* ow   = (const float*)d_in[13];
    float* out = (float*)d_out;

    const size_t MB = 1u << 20;
    char* wsb = (char*)d_ws;
    float* qf = (float*)(wsb + 0 * MB);
    float* kf = (float*)(wsb + 16 * MB);
    float* vf = (float*)(wsb + 32 * MB);
    u16*  aobf = (u16*)(wsb + 48 * MB);
    u16*  owbf = (u16*)(wsb + 56 * MB);
    unsigned int* idxbuf = (unsigned int*)(wsb + 58 * MB);
    float* wtbuf = (float*)(idxbuf + 24 * CAP);
    unsigned int* counts = (unsigned int*)(wtbuf + 24 * CAP);

    hipMemsetAsync(d_ws, 0, 48 * MB, stream);          // zero qf/kf/vf accumulators
    hipMemsetAsync(counts, 0, 256, stream);            // zero routing counters

    hipLaunchKernelGGL(router_kernel, dim3(256), dim3(256), 0, stream,
                       x, rq, rk, rv, counts, idxbuf, wtbuf);
    hipLaunchKernelGGL(cvt_bf16_kernel, dim3(1024), dim3(256), 0, stream,
                       ow, owbf, 1024 * 1024 / 4);
    hipLaunchKernelGGL(expert_kernel, dim3(24 * 48), dim3(256), 0, stream,
                       x, qw1, qw2, kw1, kw2, vw1, vw2,
                       counts, idxbuf, wtbuf, qf, kf, vf);
    hipLaunchKernelGGL(rope_kernel, dim3(16384), dim3(256), 0, stream,
                       qf, kf, pid, cosb, sinb);
    hipLaunchKernelGGL(attn_kernel, dim3(1024), dim3(256), 0, stream,
                       qf, kf, vf, aobf);
    hipLaunchKernelGGL(oproj_kernel, dim3(256), dim3(256), 0, stream,
                       aobf, owbf, out);
}

// Round 3
// 440.191 us; speedup vs baseline: 2.9569x; 2.3614x over previous
//
#include <hip/hip_runtime.h>
#include <math.h>

#define BB 4
#define TT 1024
#define CCH 1024
#define HH 16
#define DD 64
#define EE 8
#define HID 128
#define CAP 8192    // entries per (proj,pair) list; mean is 65536/28 ~= 2340
#define CH 3        // chunks per list

typedef unsigned short u16;
typedef short bf16x8 __attribute__((ext_vector_type(8)));
typedef float f32x4 __attribute__((ext_vector_type(4)));

__device__ __forceinline__ u16 f2bf(float f) {
    unsigned int u = __float_as_uint(f);
    unsigned int r = (u + 0x7FFFu + ((u >> 16) & 1u)) >> 16;   // RNE
    return (u16)r;
}

// ============================================================================
// Kernel 1: router. One thread per token-head g = (b*T+t)*16+h; fp32-exact
// top-2 of 8. Tokens are binned by (proj, expert-PAIR) so the expert kernel
// can compute both experts and write each output row exactly once.
// List id: pe = p*64 + lo*8 + hi (lo<hi), 84 of 192 slots used.
// ============================================================================
__global__ __launch_bounds__(256) void router_kernel(
    const float* __restrict__ x,
    const float* __restrict__ rq, const float* __restrict__ rk, const float* __restrict__ rv,
    unsigned int* __restrict__ counts,
    unsigned int* __restrict__ idxbuf, float2* __restrict__ wtbuf)
{
    const int tid = threadIdx.x;
    const unsigned int g = blockIdx.x * 256 + tid;

    __shared__ float rS[3][64][8];
    __shared__ int lcnt[192];
    __shared__ int lbase[192];

    for (int i = tid; i < 1536; i += 256) {
        int p = i >> 9, rem = i & 511;
        const float* rp = (p == 0) ? rq : (p == 1) ? rk : rv;
        rS[p][rem >> 3][rem & 7] = rp[rem];
    }
    if (tid < 192) lcnt[tid] = 0;
    __syncthreads();

    float lg[3][8];
    #pragma unroll
    for (int p = 0; p < 3; ++p)
        #pragma unroll
        for (int e = 0; e < 8; ++e) lg[p][e] = 0.f;

    const float* xr = x + (size_t)g * 64;
    for (int i4 = 0; i4 < 16; ++i4) {
        float4 xv = ((const float4*)xr)[i4];
        float xa[4] = {xv.x, xv.y, xv.z, xv.w};
        #pragma unroll
        for (int m = 0; m < 4; ++m) {
            int d = i4 * 4 + m;
            #pragma unroll
            for (int p = 0; p < 3; ++p) {
                float4 r0 = *(const float4*)&rS[p][d][0];
                float4 r1 = *(const float4*)&rS[p][d][4];
                lg[p][0] += xa[m] * r0.x; lg[p][1] += xa[m] * r0.y;
                lg[p][2] += xa[m] * r0.z; lg[p][3] += xa[m] * r0.w;
                lg[p][4] += xa[m] * r1.x; lg[p][5] += xa[m] * r1.y;
                lg[p][6] += xa[m] * r1.z; lg[p][7] += xa[m] * r1.w;
            }
        }
    }

    int ppe[3]; float2 pw[3]; int slot[3];
    #pragma unroll
    for (int p = 0; p < 3; ++p) {
        int i1 = 0; float v1 = lg[p][0];
        #pragma unroll
        for (int e = 1; e < 8; ++e) { if (lg[p][e] > v1) { v1 = lg[p][e]; i1 = e; } }
        int i2 = -1; float v2 = -3.402823466e38f;
        #pragma unroll
        for (int e = 0; e < 8; ++e) { if (e != i1 && lg[p][e] > v2) { v2 = lg[p][e]; i2 = e; } }
        float z = __expf(v2 - v1);
        float inv = 1.f / (1.f + z);
        float wa = inv, wb = z * inv;         // weight of i1, i2
        int lo = min(i1, i2), hi = max(i1, i2);
        float wlo = (i1 < i2) ? wa : wb;
        float whi = (i1 < i2) ? wb : wa;
        int pel = p * 64 + lo * 8 + hi;
        ppe[p] = pel; pw[p] = make_float2(wlo, whi);
        slot[p] = atomicAdd(&lcnt[pel], 1);
    }
    __syncthreads();
    if (tid < 192) {
        int c = lcnt[tid];
        lbase[tid] = c ? (int)atomicAdd(&counts[tid], (unsigned int)c) : 0;
    }
    __syncthreads();
    #pragma unroll
    for (int p = 0; p < 3; ++p) {
        int pos = lbase[ppe[p]] + slot[p];
        if (pos < CAP) {
            idxbuf[ppe[p] * CAP + pos] = g;
            wtbuf[ppe[p] * CAP + pos]  = pw[p];
        }
    }
}

// ============================================================================
// Kernel 2: pair-grouped expert MLP, bf16 MFMA. Block = (p, pair, chunk).
// Stages both experts' weights transposed in LDS once; per 64-token tile:
// gather x -> bf16 LDS, MFMA (64->128), gelu, MFMA (128->64), combine with
// router weights, RoPE (p<2), ONE non-atomic bf16 write per output element.
// ============================================================================
__global__ __launch_bounds__(256) void expert_kernel(
    const float* __restrict__ x, const int* __restrict__ pos_ids,
    const float* __restrict__ cosb, const float* __restrict__ sinb,
    const float* __restrict__ w1q, const float* __restrict__ w2q,
    const float* __restrict__ w1k, const float* __restrict__ w2k,
    const float* __restrict__ w1v, const float* __restrict__ w2v,
    const unsigned int* __restrict__ counts,
    const unsigned int* __restrict__ idxbuf, const float2* __restrict__ wtbuf,
    u16* __restrict__ qb, u16* __restrict__ kb, u16* __restrict__ vb)
{
    const int tid = threadIdx.x;
    const int pe = blockIdx.x / CH, chunk = blockIdx.x - pe * CH;
    const int p = pe >> 6, pair = pe & 63, lo = pair >> 3, hi = pair & 7;
    if (lo >= hi) return;
    int n = (int)counts[pe]; if (n == 0) return; if (n > CAP) n = CAP;

    const float* w1base = (p == 0) ? w1q : (p == 1) ? w1k : w1v;
    const float* w2base = (p == 0) ? w2q : (p == 1) ? w2k : w2v;
    u16* outp = (p == 0) ? qb : (p == 1) ? kb : vb;
    const unsigned int* il = idxbuf + pe * CAP;
    const float2* wl = wtbuf + pe * CAP;

    __shared__ u16 w1t[2][128][72];    // [e][f][d]  B-operand of GEMM1
    __shared__ u16 w2t[2][64][136];    // [e][g][f]  B-operand of GEMM2
    __shared__ u16 xs[64][72];         // [tok][d]   A-operand of GEMM1
    __shared__ u16 hs[2][64][136];     // [e][tok][f] A-operand of GEMM2
    __shared__ float2 swt[64];
    __shared__ int spos[64];
    __shared__ unsigned int sbase[64];
    __shared__ unsigned int sg[64];
    __shared__ unsigned char svalid[64];

    // ---- stage both experts' weights, bf16-transposed (once per block) ----
    #pragma unroll
    for (int e = 0; e < 2; ++e) {
        int ex = e ? hi : lo;
        const float* w1 = w1base + ex * 64 * 128;   // [d][f]
        const float* w2 = w2base + ex * 128 * 64;   // [f][g]
        for (int i = tid; i < 8192; i += 256) {
            int f = i & 127, d = i >> 7;
            w1t[e][f][d] = f2bf(w1[i]);
        }
        for (int i = tid; i < 8192; i += 256) {
            int gc = i & 63, f = i >> 6;
            w2t[e][gc][f] = f2bf(w2[i]);
        }
    }

    const int lane = tid & 63, w = tid >> 6, quad = lane >> 4, m16 = lane & 15;

    const int tiles = (n + 63) >> 6;
    for (int t = chunk; t < tiles; t += CH) {
        __syncthreads();
        if (tid < 64) {
            int j = t * 64 + tid;
            int valid = (j < n);
            int jc = valid ? j : (n - 1);
            unsigned int g = il[jc];
            float2 wv = wl[jc];
            swt[tid] = valid ? wv : make_float2(0.f, 0.f);
            svalid[tid] = (unsigned char)valid;
            sg[tid] = g;
            unsigned int b_ = g >> 14, h_ = g & 15, t_ = (g >> 4) & 1023;
            sbase[tid] = ((b_ * 16 + h_) * 1024 + t_) * 64;
            spos[tid] = pos_ids[b_ * 1024 + t_];
        }
        __syncthreads();
        // ---- gather x tile -> bf16 LDS ----
        {
            int row = tid >> 2, cg = tid & 3;
            const float* xr = x + (size_t)sg[row] * 64 + cg * 16;
            u16 tmp[16];
            #pragma unroll
            for (int c = 0; c < 4; ++c) {
                float4 v = ((const float4*)xr)[c];
                tmp[c * 4 + 0] = f2bf(v.x); tmp[c * 4 + 1] = f2bf(v.y);
                tmp[c * 4 + 2] = f2bf(v.z); tmp[c * 4 + 3] = f2bf(v.w);
            }
            u16* dst = &xs[row][cg * 16];
            #pragma unroll
            for (int c = 0; c < 4; ++c)
                ((uint2*)dst)[c] = make_uint2(
                    (unsigned)tmp[c*4+0] | ((unsigned)tmp[c*4+1] << 16),
                    (unsigned)tmp[c*4+2] | ((unsigned)tmp[c*4+3] << 16));
        }
        __syncthreads();

        // ---- phase 1: hidden = gelu(x @ w1). wave w owns n-tiles {2w,2w+1} ----
        bf16x8 xa[4][2];
        #pragma unroll
        for (int mt = 0; mt < 4; ++mt)
            #pragma unroll
            for (int kk = 0; kk < 2; ++kk)
                xa[mt][kk] = *(const bf16x8*)&xs[16 * mt + m16][8 * quad + 32 * kk];
        #pragma unroll
        for (int e = 0; e < 2; ++e) {
            #pragma unroll
            for (int ntl = 0; ntl < 2; ++ntl) {
                int nt = 2 * w + ntl;
                bf16x8 b0 = *(const bf16x8*)&w1t[e][16 * nt + m16][8 * quad];
                bf16x8 b1 = *(const bf16x8*)&w1t[e][16 * nt + m16][8 * quad + 32];
                #pragma unroll
                for (int mt = 0; mt < 4; ++mt) {
                    f32x4 acc = (f32x4){0.f, 0.f, 0.f, 0.f};
                    acc = __builtin_amdgcn_mfma_f32_16x16x32_bf16(xa[mt][0], b0, acc, 0, 0, 0);
                    acc = __builtin_amdgcn_mfma_f32_16x16x32_bf16(xa[mt][1], b1, acc, 0, 0, 0);
                    #pragma unroll
                    for (int reg = 0; reg < 4; ++reg) {
                        float z = acc[reg];
                        float u = 1.5957691216057308f * (z + 0.044715f * z * z * z);
                        float gl = z / (1.f + __expf(-u));
                        hs[e][16 * mt + 4 * quad + reg][16 * nt + m16] = f2bf(gl);
                    }
                }
            }
        }
        __syncthreads();

        // ---- phase 2: out = hidden @ w2. wave w owns token rows 16w..16w+15 ----
        bf16x8 ha[2][4];
        #pragma unroll
        for (int e = 0; e < 2; ++e)
            #pragma unroll
            for (int kk = 0; kk < 4; ++kk)
                ha[e][kk] = *(const bf16x8*)&hs[e][16 * w + m16][8 * quad + 32 * kk];
        f32x4 a2[2][4];
        #pragma unroll
        for (int e = 0; e < 2; ++e)
            #pragma unroll
            for (int nt = 0; nt < 4; ++nt) {
                f32x4 acc = (f32x4){0.f, 0.f, 0.f, 0.f};
                #pragma unroll
                for (int kk = 0; kk < 4; ++kk) {
                    bf16x8 bw = *(const bf16x8*)&w2t[e][16 * nt + m16][8 * quad + 32 * kk];
                    acc = __builtin_amdgcn_mfma_f32_16x16x32_bf16(ha[e][kk], bw, acc, 0, 0, 0);
                }
                a2[e][nt] = acc;
            }

        // ---- combine experts + RoPE + store ----
        float wlo[4], whi[4]; int rpos[4]; unsigned int rbase[4]; bool rv[4];
        #pragma unroll
        for (int reg = 0; reg < 4; ++reg) {
            int row = 16 * w + 4 * quad + reg;
            float2 wv = swt[row];
            wlo[reg] = wv.x; whi[reg] = wv.y;
            rpos[reg] = spos[row]; rbase[reg] = sbase[row]; rv[reg] = svalid[row];
        }
        if (p < 2) {
            #pragma unroll
            for (int ntp = 0; ntp < 2; ++ntp) {
                int d = 16 * ntp + m16;
                #pragma unroll
                for (int reg = 0; reg < 4; ++reg) {
                    float v1 = wlo[reg] * a2[0][ntp][reg]     + whi[reg] * a2[1][ntp][reg];
                    float v2 = wlo[reg] * a2[0][ntp + 2][reg] + whi[reg] * a2[1][ntp + 2][reg];
                    float cd = cosb[rpos[reg] * 64 + d];
                    float sd = sinb[rpos[reg] * 64 + d];
                    if (rv[reg]) {
                        outp[rbase[reg] + d]      = f2bf(v1 * cd - v2 * sd);
                        outp[rbase[reg] + d + 32] = f2bf(v2 * cd + v1 * sd);
                    }
                }
            }
        } else {
            #pragma unroll
            for (int nt = 0; nt < 4; ++nt) {
                int d = 16 * nt + m16;
                #pragma unroll
                for (int reg = 0; reg < 4; ++reg) {
                    float v = wlo[reg] * a2[0][nt][reg] + whi[reg] * a2[1][nt][reg];
                    if (rv[reg]) outp[rbase[reg] + d] = f2bf(v);
                }
            }
        }
    }
}

// ============================================================================
// Kernel 3: fp32 -> bf16 convert (for o_w)
// ============================================================================
__global__ __launch_bounds__(256) void cvt_bf16_kernel(
    const float* __restrict__ in, u16* __restrict__ out, int n4)
{
    int i = blockIdx.x * 256 + threadIdx.x;
    if (i >= n4) return;
    float4 v = ((const float4*)in)[i];
    unsigned int lov = (unsigned int)f2bf(v.x) | ((unsigned int)f2bf(v.y) << 16);
    unsigned int hiv = (unsigned int)f2bf(v.z) | ((unsigned int)f2bf(v.w) << 16);
    ((uint2*)out)[i] = make_uint2(lov, hiv);
}

// ============================================================================
// Kernel 4: flash attention, bf16 MFMA 16x16x32, fp32 softmax/accum.
// Inputs are bf16 planes [B,H,T,D]. Block = (b,h,64-row q-tile), 4 waves.
// ============================================================================
__global__ __launch_bounds__(256) void attn_kernel(
    const u16* __restrict__ qbp, const u16* __restrict__ kbp,
    const u16* __restrict__ vbp, u16* __restrict__ ao)
{
    const int tid = threadIdx.x;
    const int qt = blockIdx.x & 15, h = (blockIdx.x >> 4) & 15, b = blockIdx.x >> 8;
    const int q0 = qt * 64;
    const size_t plane = ((size_t)(b * 16 + h)) * 1024 * 64;
    const u16* qp = qbp + plane;
    const u16* kp = kbp + plane;
    const u16* vp = vbp + plane;

    const int w = tid >> 6, lane = tid & 63, quad = lane >> 4, m16 = lane & 15;

    __shared__ u16 Qs[64][72];
    __shared__ u16 Ks[64][72];
    __shared__ u16 Vt[64][72];        // [d][kj]
    __shared__ u16 Ps[4][16][72];     // per-wave P scratch

    // stage Q (once): 16 elems (32B) per thread
    {
        int row = tid >> 2, seg = tid & 3;
        const uint4* src = (const uint4*)&qp[(size_t)(q0 + row) * 64 + seg * 16];
        uint4 v0 = src[0], v1 = src[1];
        uint4* dst = (uint4*)&Qs[row][seg * 16];
        dst[0] = v0; dst[1] = v1;
    }
    float m_r[4], l_r[4];
    #pragma unroll
    for (int i = 0; i < 4; ++i) { m_r[i] = -1e30f; l_r[i] = 0.f; }
    f32x4 oacc[4];
    #pragma unroll
    for (int i = 0; i < 4; ++i) oacc[i] = (f32x4){0.f, 0.f, 0.f, 0.f};

    for (int kt = 0; kt <= qt; ++kt) {
        const int k0 = kt * 64;
        __syncthreads();
        {
            int row = tid >> 2, seg = tid & 3;
            const uint4* src = (const uint4*)&kp[(size_t)(k0 + row) * 64 + seg * 16];
            uint4 v0 = src[0], v1 = src[1];
            uint4* dst = (uint4*)&Ks[row][seg * 16];
            dst[0] = v0; dst[1] = v1;
        }
        {
            int kj = tid & 63, dg = tid >> 6;
            #pragma unroll
            for (int pp = 0; pp < 4; ++pp) {
                int d0 = dg * 4 + pp * 16;
                ushort4 v = *(const ushort4*)&vp[(size_t)(k0 + kj) * 64 + d0];
                Vt[d0 + 0][kj] = v.x; Vt[d0 + 1][kj] = v.y;
                Vt[d0 + 2][kj] = v.z; Vt[d0 + 3][kj] = v.w;
            }
        }
        __syncthreads();

        bf16x8 aq0 = *(const bf16x8*)&Qs[16 * w + m16][8 * quad];
        bf16x8 aq1 = *(const bf16x8*)&Qs[16 * w + m16][32 + 8 * quad];
        f32x4 sv[4];
        #pragma unroll
        for (int ct = 0; ct < 4; ++ct) {
            bf16x8 bk0 = *(const bf16x8*)&Ks[16 * ct + m16][8 * quad];
            bf16x8 bk1 = *(const bf16x8*)&Ks[16 * ct + m16][32 + 8 * quad];
            f32x4 acc = (f32x4){0.f, 0.f, 0.f, 0.f};
            acc = __builtin_amdgcn_mfma_f32_16x16x32_bf16(aq0, bk0, acc, 0, 0, 0);
            acc = __builtin_amdgcn_mfma_f32_16x16x32_bf16(aq1, bk1, acc, 0, 0, 0);
            sv[ct] = acc;
        }

        float s[4][4];
        const bool diag = (kt == qt);
        #pragma unroll
        for (int ct = 0; ct < 4; ++ct)
            #pragma unroll
            for (int reg = 0; reg < 4; ++reg) {
                float v = sv[ct][reg] * 0.125f;
                if (diag) {
                    int col = 16 * ct + m16;
                    int row = 16 * w + 4 * quad + reg;
                    if (col > row) v = -1e30f;
                }
                s[ct][reg] = v;
            }

        float nm[4], al[4];
        #pragma unroll
        for (int reg = 0; reg < 4; ++reg) {
            float rm = fmaxf(fmaxf(s[0][reg], s[1][reg]), fmaxf(s[2][reg], s[3][reg]));
            #pragma unroll
            for (int off = 1; off < 16; off <<= 1) rm = fmaxf(rm, __shfl_xor(rm, off, 16));
            float mn = fmaxf(m_r[reg], rm);
            nm[reg] = mn;
            al[reg] = __expf(m_r[reg] - mn);
        }
        #pragma unroll
        for (int reg = 0; reg < 4; ++reg) {
            float sum = 0.f;
            #pragma unroll
            for (int ct = 0; ct < 4; ++ct) {
                float pv = __expf(s[ct][reg] - nm[reg]);
                s[ct][reg] = pv;
                sum += pv;
            }
            #pragma unroll
            for (int off = 1; off < 16; off <<= 1) sum += __shfl_xor(sum, off, 16);
            l_r[reg] = l_r[reg] * al[reg] + sum;
            m_r[reg] = nm[reg];
        }

        #pragma unroll
        for (int ct = 0; ct < 4; ++ct)
            #pragma unroll
            for (int reg = 0; reg < 4; ++reg)
                Ps[w][4 * quad + reg][16 * ct + m16] = f2bf(s[ct][reg]);

        #pragma unroll
        for (int dt = 0; dt < 4; ++dt)
            #pragma unroll
            for (int reg = 0; reg < 4; ++reg) oacc[dt][reg] *= al[reg];

        bf16x8 ap0 = *(const bf16x8*)&Ps[w][m16][8 * quad];
        bf16x8 ap1 = *(const bf16x8*)&Ps[w][m16][32 + 8 * quad];
        #pragma unroll
        for (int dt = 0; dt < 4; ++dt) {
            bf16x8 bv0 = *(const bf16x8*)&Vt[16 * dt + m16][8 * quad];
            bf16x8 bv1 = *(const bf16x8*)&Vt[16 * dt + m16][32 + 8 * quad];
            oacc[dt] = __builtin_amdgcn_mfma_f32_16x16x32_bf16(ap0, bv0, oacc[dt], 0, 0, 0);
            oacc[dt] = __builtin_amdgcn_mfma_f32_16x16x32_bf16(ap1, bv1, oacc[dt], 0, 0, 0);
        }
    }

    #pragma unroll
    for (int reg = 0; reg < 4; ++reg) {
        float linv = 1.f / l_r[reg];
        int row = q0 + 16 * w + 4 * quad + reg;
        size_t base = ((size_t)(b * 1024) + row) * 1024 + h * 64;
        #pragma unroll
        for (int dt = 0; dt < 4; ++dt)
            ao[base + 16 * dt + m16] = f2bf(oacc[dt][reg] * linv);
    }
}

// ============================================================================
// Kernel 5: output projection, bf16 MFMA gemm_bt. 128x128 tile, BK=32.
// ============================================================================
__global__ __launch_bounds__(256) void oproj_kernel(
    const u16* __restrict__ A, const u16* __restrict__ Bw,
    float* __restrict__ out)
{
    const int tid = threadIdx.x;
    const int bn = blockIdx.x & 7;
    const int bm = blockIdx.x >> 3;
    const int m0 = bm * 128, n0 = bn * 128;
    const int w = tid >> 6, lane = tid & 63, quad = lane >> 4, m16 = lane & 15;
    const int wm = (w >> 1) * 64, wn = (w & 1) * 64;

    __shared__ u16 As[128][32];
    __shared__ u16 Bs[128][32];

    f32x4 acc[4][4];
    #pragma unroll
    for (int mt = 0; mt < 4; ++mt)
        #pragma unroll
        for (int nt = 0; nt < 4; ++nt) acc[mt][nt] = (f32x4){0.f, 0.f, 0.f, 0.f};

    for (int k0 = 0; k0 < 1024; k0 += 32) {
        __syncthreads();
        {
            int row = tid >> 1, sg = (tid & 1) * 16;
            const uint4* srcA = (const uint4*)&A[(size_t)(m0 + row) * 1024 + k0 + sg];
            uint4 a0 = srcA[0], a1 = srcA[1];
            uint4* dstA = (uint4*)&As[row][sg];
            dstA[0] = a0; dstA[1] = a1;
            const uint4* srcB = (const uint4*)&Bw[(size_t)(n0 + row) * 1024 + k0 + sg];
            uint4 b0 = srcB[0], b1 = srcB[1];
            uint4* dstB = (uint4*)&Bs[row][sg];
            dstB[0] = b0; dstB[1] = b1;
        }
        __syncthreads();
        bf16x8 af[4], bf_[4];
        #pragma unroll
        for (int mt = 0; mt < 4; ++mt) af[mt] = *(const bf16x8*)&As[wm + 16 * mt + m16][8 * quad];
        #pragma unroll
        for (int nt = 0; nt < 4; ++nt) bf_[nt] = *(const bf16x8*)&Bs[wn + 16 * nt + m16][8 * quad];
        #pragma unroll
        for (int mt = 0; mt < 4; ++mt)
            #pragma unroll
            for (int nt = 0; nt < 4; ++nt)
                acc[mt][nt] = __builtin_amdgcn_mfma_f32_16x16x32_bf16(af[mt], bf_[nt], acc[mt][nt], 0, 0, 0);
    }
    #pragma unroll
    for (int mt = 0; mt < 4; ++mt)
        #pragma unroll
        for (int nt = 0; nt < 4; ++nt)
            #pragma unroll
            for (int reg = 0; reg < 4; ++reg)
                out[(size_t)(m0 + wm + 16 * mt + 4 * quad + reg) * 1024 + n0 + wn + 16 * nt + m16] =
                    acc[mt][nt][reg];
}

// ============================================================================
extern "C" void kernel_launch(void* const* d_in, const int* in_sizes, int n_in,
                              void* d_out, int out_size, void* d_ws, size_t ws_size,
                              hipStream_t stream) {
    (void)in_sizes; (void)n_in; (void)out_size; (void)ws_size;
    const float* x    = (const float*)d_in[0];
    const int*   pid  = (const int*)  d_in[1];
    const float* cosb = (const float*)d_in[2];
    const float* sinb = (const float*)d_in[3];
    const float* rq   = (const float*)d_in[4];
    const float* rk   = (const float*)d_in[5];
    const float* rv   = (const float*)d_in[6];
    const float* qw1  = (const float*)d_in[7];
    const float* qw2  = (const float*)d_in[8];
    const float* kw1  = (const float*)d_in[9];
    const float* kw2  = (const float*)d_in[10];
    const float* vw1  = (const float*)d_in[11];
    const float* vw2  = (const float*)d_in[12];
    const float* ow   = (const float*)d_in[13];
    float* out = (float*)d_out;

    const size_t MB = 1u << 20;
    char* wsb = (char*)d_ws;
    u16* qb   = (u16*)(wsb + 0 * MB);      // 8 MB  bf16 [B,H,T,D]
    u16* kb   = (u16*)(wsb + 8 * MB);      // 8 MB
    u16* vb   = (u16*)(wsb + 16 * MB);     // 8 MB
    u16* aobf = (u16*)(wsb + 24 * MB);     // 8 MB  bf16 [B,T,C]
    u16* owbf = (u16*)(wsb + 32 * MB);     // 2 MB  bf16 o_w
    unsigned int* idxbuf = (unsigned int*)(wsb + 34 * MB);       // 6 MB
    float2*       wtbuf  = (float2*)(wsb + 41 * MB);             // 12 MB
    unsigned int* counts = (unsigned int*)(wsb + 54 * MB);       // 768 B

    hipMemsetAsync(counts, 0, 1024, stream);

    hipLaunchKernelGGL(router_kernel, dim3(256), dim3(256), 0, stream,
                       x, rq, rk, rv, counts, idxbuf, wtbuf);
    hipLaunchKernelGGL(cvt_bf16_kernel, dim3(1024), dim3(256), 0, stream,
                       ow, owbf, 1024 * 1024 / 4);
    hipLaunchKernelGGL(expert_kernel, dim3(192 * CH), dim3(256), 0, stream,
                       x, pid, cosb, sinb, qw1, qw2, kw1, kw2, vw1, vw2,
                       counts, idxbuf, wtbuf, qb, kb, vb);
    hipLaunchKernelGGL(attn_kernel, dim3(1024), dim3(256), 0, stream,
                       qb, kb, vb, aobf);
    hipLaunchKernelGGL(oproj_kernel, dim3(256), dim3(256), 0, stream,
                       aobf, owbf, out);
}

// Round 4
// 295.821 us; speedup vs baseline: 4.3999x; 1.4880x over previous
//
#include <hip/hip_runtime.h>
#include <math.h>

#define BB 4
#define TT 1024
#define CCH 1024
#define HH 16
#define DD 64
#define EE 8
#define HID 128
#define CAP 8192    // entries per (proj,pair) list; mean is 65536/28 ~= 2340
#define CH 3        // chunk-blocks per (proj,pair) list

typedef unsigned short u16;
typedef short bf16x8 __attribute__((ext_vector_type(8)));
typedef float f32x4 __attribute__((ext_vector_type(4)));

__device__ __forceinline__ u16 f2bf(float f) {
    unsigned int u = __float_as_uint(f);
    unsigned int r = (u + 0x7FFFu + ((u >> 16) & 1u)) >> 16;   // RNE
    return (u16)r;
}

// ============================================================================
// Kernel 1: router. One thread per token-head g = (b*T+t)*16+h; fp32-exact
// top-2 of 8. Tokens binned by (proj, expert-PAIR): pe = p*64 + lo*8 + hi.
// ============================================================================
__global__ __launch_bounds__(256) void router_kernel(
    const float* __restrict__ x,
    const float* __restrict__ rq, const float* __restrict__ rk, const float* __restrict__ rv,
    unsigned int* __restrict__ counts,
    unsigned int* __restrict__ idxbuf, float2* __restrict__ wtbuf)
{
    const int tid = threadIdx.x;
    const unsigned int g = blockIdx.x * 256 + tid;

    __shared__ float rS[3][64][8];
    __shared__ int lcnt[192];
    __shared__ int lbase[192];

    for (int i = tid; i < 1536; i += 256) {
        int p = i >> 9, rem = i & 511;
        const float* rp = (p == 0) ? rq : (p == 1) ? rk : rv;
        rS[p][rem >> 3][rem & 7] = rp[rem];
    }
    if (tid < 192) lcnt[tid] = 0;
    __syncthreads();

    float lg[3][8];
    #pragma unroll
    for (int p = 0; p < 3; ++p)
        #pragma unroll
        for (int e = 0; e < 8; ++e) lg[p][e] = 0.f;

    const float* xr = x + (size_t)g * 64;
    for (int i4 = 0; i4 < 16; ++i4) {
        float4 xv = ((const float4*)xr)[i4];
        float xa[4] = {xv.x, xv.y, xv.z, xv.w};
        #pragma unroll
        for (int m = 0; m < 4; ++m) {
            int d = i4 * 4 + m;
            #pragma unroll
            for (int p = 0; p < 3; ++p) {
                float4 r0 = *(const float4*)&rS[p][d][0];
                float4 r1 = *(const float4*)&rS[p][d][4];
                lg[p][0] += xa[m] * r0.x; lg[p][1] += xa[m] * r0.y;
                lg[p][2] += xa[m] * r0.z; lg[p][3] += xa[m] * r0.w;
                lg[p][4] += xa[m] * r1.x; lg[p][5] += xa[m] * r1.y;
                lg[p][6] += xa[m] * r1.z; lg[p][7] += xa[m] * r1.w;
            }
        }
    }

    int ppe[3]; float2 pw[3]; int slot[3];
    #pragma unroll
    for (int p = 0; p < 3; ++p) {
        int i1 = 0; float v1 = lg[p][0];
        #pragma unroll
        for (int e = 1; e < 8; ++e) { if (lg[p][e] > v1) { v1 = lg[p][e]; i1 = e; } }
        int i2 = -1; float v2 = -3.402823466e38f;
        #pragma unroll
        for (int e = 0; e < 8; ++e) { if (e != i1 && lg[p][e] > v2) { v2 = lg[p][e]; i2 = e; } }
        float z = __expf(v2 - v1);
        float inv = 1.f / (1.f + z);
        float wa = inv, wb = z * inv;
        int lo = min(i1, i2), hi = max(i1, i2);
        float wlo = (i1 < i2) ? wa : wb;
        float whi = (i1 < i2) ? wb : wa;
        int pel = p * 64 + lo * 8 + hi;
        ppe[p] = pel; pw[p] = make_float2(wlo, whi);
        slot[p] = atomicAdd(&lcnt[pel], 1);
    }
    __syncthreads();
    if (tid < 192) {
        int c = lcnt[tid];
        lbase[tid] = c ? (int)atomicAdd(&counts[tid], (unsigned int)c) : 0;
    }
    __syncthreads();
    #pragma unroll
    for (int p = 0; p < 3; ++p) {
        int pos = lbase[ppe[p]] + slot[p];
        if (pos < CAP) {
            idxbuf[ppe[p] * CAP + pos] = g;
            wtbuf[ppe[p] * CAP + pos]  = pw[p];
        }
    }
}

// ============================================================================
// Kernel 2: pair-grouped expert MLP, bf16 MFMA, wave-independent.
// Block = one of 84 (proj,pair) x CH chunks, 512 threads = 8 waves.
// One barrier (weight staging); then each wave grinds 16-token subtiles
// end-to-end: global-gather A-frags -> MFMA1 (kk-pipelined) -> gelu ->
// per-wave LDS scratch -> MFMA2 -> combine + RoPE -> single bf16 store.
// ============================================================================
__global__ __launch_bounds__(512) void expert_kernel(
    const float* __restrict__ x, const int* __restrict__ pos_ids,
    const float* __restrict__ cosb, const float* __restrict__ sinb,
    const float* __restrict__ w1q, const float* __restrict__ w2q,
    const float* __restrict__ w1k, const float* __restrict__ w2k,
    const float* __restrict__ w1v, const float* __restrict__ w2v,
    const unsigned int* __restrict__ counts,
    const unsigned int* __restrict__ idxbuf, const float2* __restrict__ wtbuf,
    u16* __restrict__ qb, u16* __restrict__ kb, u16* __restrict__ vb)
{
    const int tid = threadIdx.x;
    const int pe84 = blockIdx.x / CH, chunk = blockIdx.x - pe84 * CH;
    const int p = pe84 / 28;
    int q28 = pe84 - p * 28;
    int lo = 0;
    while (q28 >= 7 - lo) { q28 -= 7 - lo; ++lo; }
    const int hi = lo + 1 + q28;
    const int pe = p * 64 + lo * 8 + hi;

    int n = (int)counts[pe]; if (n == 0) return; if (n > CAP) n = CAP;

    const float* w1base = (p == 0) ? w1q : (p == 1) ? w1k : w1v;
    const float* w2base = (p == 0) ? w2q : (p == 1) ? w2k : w2v;
    u16* outp = (p == 0) ? qb : (p == 1) ? kb : vb;
    const unsigned int* il = idxbuf + pe * CAP;
    const float2* wl = wtbuf + pe * CAP;

    __shared__ u16 w1t[2][128][72];    // [e][f][d]  B-operand GEMM1   36.9 KB
    __shared__ u16 w2t[2][64][136];    // [e][g][f]  B-operand GEMM2   34.8 KB
    __shared__ u16 hsw[8][16][40];     // per-wave gelu scratch        10.2 KB

    // ---- stage both experts' weights, bf16-transposed (once) ----
    #pragma unroll
    for (int e = 0; e < 2; ++e) {
        int ex = e ? hi : lo;
        const float* w1 = w1base + ex * 64 * 128;   // [d][f]
        const float* w2 = w2base + ex * 128 * 64;   // [f][g]
        for (int i = tid; i < 8192; i += 512)
            w1t[e][i & 127][i >> 7] = f2bf(w1[i]);
        for (int i = tid; i < 8192; i += 512)
            w2t[e][i & 63][i >> 6] = f2bf(w2[i]);
    }
    __syncthreads();

    const int lane = tid & 63, w = tid >> 6, quad = lane >> 4, m16 = lane & 15;
    const int wid = chunk * 8 + w;
    const int WRK = CH * 8;
    const int nsub = (n + 15) >> 4;

    for (int s = wid; s < nsub; s += WRK) {
        const int base = s * 16;
        // ---- lane 0..15: per-token metadata; broadcast via shfl ----
        unsigned int gtok = 0, obase = 0; float wlo_ = 0.f, whi_ = 0.f;
        int posv = 0, valid = 0;
        if (lane < 16) {
            int j = base + lane;
            valid = (j < n);
            int jc = valid ? j : (n - 1);
            gtok = il[jc];
            float2 wv = wl[jc];
            wlo_ = valid ? wv.x : 0.f; whi_ = valid ? wv.y : 0.f;
            unsigned int b_ = gtok >> 14, h_ = gtok & 15, t_ = (gtok >> 4) & 1023;
            obase = ((b_ * 16 + h_) * 1024 + t_) * 64;
            posv = pos_ids[b_ * 1024 + t_];
        }
        unsigned int gm = (unsigned int)__shfl((int)gtok, m16, 64);

        // ---- A-frags: x[tok][8q..8q+8) and x[tok][32+8q..) from global ----
        const float* xr = x + (size_t)gm * 64 + 8 * quad;
        float4 xa0 = *(const float4*)(xr);
        float4 xa1 = *(const float4*)(xr + 4);
        float4 xb0 = *(const float4*)(xr + 32);
        float4 xb1 = *(const float4*)(xr + 36);
        bf16x8 A0, A1;
        A0[0] = (short)f2bf(xa0.x); A0[1] = (short)f2bf(xa0.y);
        A0[2] = (short)f2bf(xa0.z); A0[3] = (short)f2bf(xa0.w);
        A0[4] = (short)f2bf(xa1.x); A0[5] = (short)f2bf(xa1.y);
        A0[6] = (short)f2bf(xa1.z); A0[7] = (short)f2bf(xa1.w);
        A1[0] = (short)f2bf(xb0.x); A1[1] = (short)f2bf(xb0.y);
        A1[2] = (short)f2bf(xb0.z); A1[3] = (short)f2bf(xb0.w);
        A1[4] = (short)f2bf(xb1.x); A1[5] = (short)f2bf(xb1.y);
        A1[6] = (short)f2bf(xb1.z); A1[7] = (short)f2bf(xb1.w);

        f32x4 acc2[2][4];
        #pragma unroll
        for (int e = 0; e < 2; ++e)
            #pragma unroll
            for (int nt = 0; nt < 4; ++nt) acc2[e][nt] = (f32x4){0.f, 0.f, 0.f, 0.f};

        #pragma unroll
        for (int e = 0; e < 2; ++e) {
            #pragma unroll
            for (int kk = 0; kk < 4; ++kk) {
                // --- GEMM1 for 32 hidden features (n-tiles 2kk, 2kk+1) ---
                int nt0 = 2 * kk, nt1 = 2 * kk + 1;
                bf16x8 b0a = *(const bf16x8*)&w1t[e][16 * nt0 + m16][8 * quad];
                bf16x8 b0b = *(const bf16x8*)&w1t[e][16 * nt0 + m16][32 + 8 * quad];
                bf16x8 b1a = *(const bf16x8*)&w1t[e][16 * nt1 + m16][8 * quad];
                bf16x8 b1b = *(const bf16x8*)&w1t[e][16 * nt1 + m16][32 + 8 * quad];
                f32x4 c0 = (f32x4){0.f, 0.f, 0.f, 0.f};
                f32x4 c1 = (f32x4){0.f, 0.f, 0.f, 0.f};
                c0 = __builtin_amdgcn_mfma_f32_16x16x32_bf16(A0, b0a, c0, 0, 0, 0);
                c0 = __builtin_amdgcn_mfma_f32_16x16x32_bf16(A1, b0b, c0, 0, 0, 0);
                c1 = __builtin_amdgcn_mfma_f32_16x16x32_bf16(A0, b1a, c1, 0, 0, 0);
                c1 = __builtin_amdgcn_mfma_f32_16x16x32_bf16(A1, b1b, c1, 0, 0, 0);
                // --- gelu -> per-wave scratch (C-layout -> A-layout) ---
                #pragma unroll
                for (int r = 0; r < 4; ++r) {
                    float z = c0[r];
                    float u = 1.5957691216057308f * (z + 0.044715f * z * z * z);
                    hsw[w][4 * quad + r][m16] = f2bf(z / (1.f + __expf(-u)));
                    float z2 = c1[r];
                    float u2 = 1.5957691216057308f * (z2 + 0.044715f * z2 * z2 * z2);
                    hsw[w][4 * quad + r][16 + m16] = f2bf(z2 / (1.f + __expf(-u2)));
                }
                bf16x8 A2 = *(const bf16x8*)&hsw[w][m16][8 * quad];
                // --- GEMM2 partial: acc += A2 x w2[32kk..32kk+32) ---
                #pragma unroll
                for (int nt2 = 0; nt2 < 4; ++nt2) {
                    bf16x8 b2 = *(const bf16x8*)&w2t[e][16 * nt2 + m16][32 * kk + 8 * quad];
                    acc2[e][nt2] = __builtin_amdgcn_mfma_f32_16x16x32_bf16(A2, b2, acc2[e][nt2], 0, 0, 0);
                }
            }
        }

        // ---- combine experts + RoPE + store (C rows = tokens 4q+r) ----
        #pragma unroll
        for (int r = 0; r < 4; ++r) {
            int row = 4 * quad + r;
            float wlo_r = __shfl(wlo_, row, 64);
            float whi_r = __shfl(whi_, row, 64);
            int   pos_r = __shfl(posv, row, 64);
            unsigned int ob = (unsigned int)__shfl((int)obase, row, 64);
            int   val_r = __shfl(valid, row, 64);
            if (p < 2) {
                #pragma unroll
                for (int ntp = 0; ntp < 2; ++ntp) {
                    int d = 16 * ntp + m16;
                    float v1 = wlo_r * acc2[0][ntp][r]     + whi_r * acc2[1][ntp][r];
                    float v2 = wlo_r * acc2[0][ntp + 2][r] + whi_r * acc2[1][ntp + 2][r];
                    float cd = cosb[pos_r * 64 + d];
                    float sd = sinb[pos_r * 64 + d];
                    if (val_r) {
                        outp[ob + d]      = f2bf(v1 * cd - v2 * sd);
                        outp[ob + d + 32] = f2bf(v2 * cd + v1 * sd);
                    }
                }
            } else {
                #pragma unroll
                for (int nt = 0; nt < 4; ++nt) {
                    float v = wlo_r * acc2[0][nt][r] + whi_r * acc2[1][nt][r];
                    if (val_r) outp[ob + 16 * nt + m16] = f2bf(v);
                }
            }
        }
    }
}

// ============================================================================
// Kernel 3: fp32 -> bf16 convert (for o_w)
// ============================================================================
__global__ __launch_bounds__(256) void cvt_bf16_kernel(
    const float* __restrict__ in, u16* __restrict__ out, int n4)
{
    int i = blockIdx.x * 256 + threadIdx.x;
    if (i >= n4) return;
    float4 v = ((const float4*)in)[i];
    unsigned int lov = (unsigned int)f2bf(v.x) | ((unsigned int)f2bf(v.y) << 16);
    unsigned int hiv = (unsigned int)f2bf(v.z) | ((unsigned int)f2bf(v.w) << 16);
    ((uint2*)out)[i] = make_uint2(lov, hiv);
}

// ============================================================================
// Kernel 4: flash attention, bf16 MFMA 16x16x32, fp32 softmax/accum.
// Inputs are bf16 planes [B,H,T,D]. Block = (b,h,64-row q-tile), 4 waves.
// ============================================================================
__global__ __launch_bounds__(256) void attn_kernel(
    const u16* __restrict__ qbp, const u16* __restrict__ kbp,
    const u16* __restrict__ vbp, u16* __restrict__ ao)
{
    const int tid = threadIdx.x;
    const int qt = blockIdx.x & 15, h = (blockIdx.x >> 4) & 15, b = blockIdx.x >> 8;
    const int q0 = qt * 64;
    const size_t plane = ((size_t)(b * 16 + h)) * 1024 * 64;
    const u16* qp = qbp + plane;
    const u16* kp = kbp + plane;
    const u16* vp = vbp + plane;

    const int w = tid >> 6, lane = tid & 63, quad = lane >> 4, m16 = lane & 15;

    __shared__ u16 Qs[64][72];
    __shared__ u16 Ks[64][72];
    __shared__ u16 Vt[64][72];        // [d][kj]
    __shared__ u16 Ps[4][16][72];     // per-wave P scratch

    {
        int row = tid >> 2, seg = tid & 3;
        const uint4* src = (const uint4*)&qp[(size_t)(q0 + row) * 64 + seg * 16];
        uint4 v0 = src[0], v1 = src[1];
        uint4* dst = (uint4*)&Qs[row][seg * 16];
        dst[0] = v0; dst[1] = v1;
    }
    float m_r[4], l_r[4];
    #pragma unroll
    for (int i = 0; i < 4; ++i) { m_r[i] = -1e30f; l_r[i] = 0.f; }
    f32x4 oacc[4];
    #pragma unroll
    for (int i = 0; i < 4; ++i) oacc[i] = (f32x4){0.f, 0.f, 0.f, 0.f};

    for (int kt = 0; kt <= qt; ++kt) {
        const int k0 = kt * 64;
        __syncthreads();
        {
            int row = tid >> 2, seg = tid & 3;
            const uint4* src = (const uint4*)&kp[(size_t)(k0 + row) * 64 + seg * 16];
            uint4 v0 = src[0], v1 = src[1];
            uint4* dst = (uint4*)&Ks[row][seg * 16];
            dst[0] = v0; dst[1] = v1;
        }
        {
            int kj = tid & 63, dg = tid >> 6;
            #pragma unroll
            for (int pp = 0; pp < 4; ++pp) {
                int d0 = dg * 4 + pp * 16;
                ushort4 v = *(const ushort4*)&vp[(size_t)(k0 + kj) * 64 + d0];
                Vt[d0 + 0][kj] = v.x; Vt[d0 + 1][kj] = v.y;
                Vt[d0 + 2][kj] = v.z; Vt[d0 + 3][kj] = v.w;
            }
        }
        __syncthreads();

        bf16x8 aq0 = *(const bf16x8*)&Qs[16 * w + m16][8 * quad];
        bf16x8 aq1 = *(const bf16x8*)&Qs[16 * w + m16][32 + 8 * quad];
        f32x4 sv[4];
        #pragma unroll
        for (int ct = 0; ct < 4; ++ct) {
            bf16x8 bk0 = *(const bf16x8*)&Ks[16 * ct + m16][8 * quad];
            bf16x8 bk1 = *(const bf16x8*)&Ks[16 * ct + m16][32 + 8 * quad];
            f32x4 acc = (f32x4){0.f, 0.f, 0.f, 0.f};
            acc = __builtin_amdgcn_mfma_f32_16x16x32_bf16(aq0, bk0, acc, 0, 0, 0);
            acc = __builtin_amdgcn_mfma_f32_16x16x32_bf16(aq1, bk1, acc, 0, 0, 0);
            sv[ct] = acc;
        }

        float s[4][4];
        const bool diag = (kt == qt);
        #pragma unroll
        for (int ct = 0; ct < 4; ++ct)
            #pragma unroll
            for (int reg = 0; reg < 4; ++reg) {
                float v = sv[ct][reg] * 0.125f;
                if (diag) {
                    int col = 16 * ct + m16;
                    int row = 16 * w + 4 * quad + reg;
                    if (col > row) v = -1e30f;
                }
                s[ct][reg] = v;
            }

        float nm[4], al[4];
        #pragma unroll
        for (int reg = 0; reg < 4; ++reg) {
            float rm = fmaxf(fmaxf(s[0][reg], s[1][reg]), fmaxf(s[2][reg], s[3][reg]));
            #pragma unroll
            for (int off = 1; off < 16; off <<= 1) rm = fmaxf(rm, __shfl_xor(rm, off, 16));
            float mn = fmaxf(m_r[reg], rm);
            nm[reg] = mn;
            al[reg] = __expf(m_r[reg] - mn);
        }
        #pragma unroll
        for (int reg = 0; reg < 4; ++reg) {
            float sum = 0.f;
            #pragma unroll
            for (int ct = 0; ct < 4; ++ct) {
                float pv = __expf(s[ct][reg] - nm[reg]);
                s[ct][reg] = pv;
                sum += pv;
            }
            #pragma unroll
            for (int off = 1; off < 16; off <<= 1) sum += __shfl_xor(sum, off, 16);
            l_r[reg] = l_r[reg] * al[reg] + sum;
            m_r[reg] = nm[reg];
        }

        #pragma unroll
        for (int ct = 0; ct < 4; ++ct)
            #pragma unroll
            for (int reg = 0; reg < 4; ++reg)
                Ps[w][4 * quad + reg][16 * ct + m16] = f2bf(s[ct][reg]);

        #pragma unroll
        for (int dt = 0; dt < 4; ++dt)
            #pragma unroll
            for (int reg = 0; reg < 4; ++reg) oacc[dt][reg] *= al[reg];

        bf16x8 ap0 = *(const bf16x8*)&Ps[w][m16][8 * quad];
        bf16x8 ap1 = *(const bf16x8*)&Ps[w][m16][32 + 8 * quad];
        #pragma unroll
        for (int dt = 0; dt < 4; ++dt) {
            bf16x8 bv0 = *(const bf16x8*)&Vt[16 * dt + m16][8 * quad];
            bf16x8 bv1 = *(const bf16x8*)&Vt[16 * dt + m16][32 + 8 * quad];
            oacc[dt] = __builtin_amdgcn_mfma_f32_16x16x32_bf16(ap0, bv0, oacc[dt], 0, 0, 0);
            oacc[dt] = __builtin_amdgcn_mfma_f32_16x16x32_bf16(ap1, bv1, oacc[dt], 0, 0, 0);
        }
    }

    #pragma unroll
    for (int reg = 0; reg < 4; ++reg) {
        float linv = 1.f / l_r[reg];
        int row = q0 + 16 * w + 4 * quad + reg;
        size_t base = ((size_t)(b * 1024) + row) * 1024 + h * 64;
        #pragma unroll
        for (int dt = 0; dt < 4; ++dt)
            ao[base + 16 * dt + m16] = f2bf(oacc[dt][reg] * linv);
    }
}

// ============================================================================
// Kernel 5: output projection, bf16 MFMA gemm_bt. 128x128 tile, BK=32.
// ============================================================================
__global__ __launch_bounds__(256) void oproj_kernel(
    const u16* __restrict__ A, const u16* __restrict__ Bw,
    float* __restrict__ out)
{
    const int tid = threadIdx.x;
    const int bn = blockIdx.x & 7;
    const int bm = blockIdx.x >> 3;
    const int m0 = bm * 128, n0 = bn * 128;
    const int w = tid >> 6, lane = tid & 63, quad = lane >> 4, m16 = lane & 15;
    const int wm = (w >> 1) * 64, wn = (w & 1) * 64;

    __shared__ u16 As[128][32];
    __shared__ u16 Bs[128][32];

    f32x4 acc[4][4];
    #pragma unroll
    for (int mt = 0; mt < 4; ++mt)
        #pragma unroll
        for (int nt = 0; nt < 4; ++nt) acc[mt][nt] = (f32x4){0.f, 0.f, 0.f, 0.f};

    for (int k0 = 0; k0 < 1024; k0 += 32) {
        __syncthreads();
        {
            int row = tid >> 1, sg = (tid & 1) * 16;
            const uint4* srcA = (const uint4*)&A[(size_t)(m0 + row) * 1024 + k0 + sg];
            uint4 a0 = srcA[0], a1 = srcA[1];
            uint4* dstA = (uint4*)&As[row][sg];
            dstA[0] = a0; dstA[1] = a1;
            const uint4* srcB = (const uint4*)&Bw[(size_t)(n0 + row) * 1024 + k0 + sg];
            uint4 b0 = srcB[0], b1 = srcB[1];
            uint4* dstB = (uint4*)&Bs[row][sg];
            dstB[0] = b0; dstB[1] = b1;
        }
        __syncthreads();
        bf16x8 af[4], bf_[4];
        #pragma unroll
        for (int mt = 0; mt < 4; ++mt) af[mt] = *(const bf16x8*)&As[wm + 16 * mt + m16][8 * quad];
        #pragma unroll
        for (int nt = 0; nt < 4; ++nt) bf_[nt] = *(const bf16x8*)&Bs[wn + 16 * nt + m16][8 * quad];
        #pragma unroll
        for (int mt = 0; mt < 4; ++mt)
            #pragma unroll
            for (int nt = 0; nt < 4; ++nt)
                acc[mt][nt] = __builtin_amdgcn_mfma_f32_16x16x32_bf16(af[mt], bf_[nt], acc[mt][nt], 0, 0, 0);
    }
    #pragma unroll
    for (int mt = 0; mt < 4; ++mt)
        #pragma unroll
        for (int nt = 0; nt < 4; ++nt)
            #pragma unroll
            for (int reg = 0; reg < 4; ++reg)
                out[(size_t)(m0 + wm + 16 * mt + 4 * quad + reg) * 1024 + n0 + wn + 16 * nt + m16] =
                    acc[mt][nt][reg];
}

// ============================================================================
extern "C" void kernel_launch(void* const* d_in, const int* in_sizes, int n_in,
                              void* d_out, int out_size, void* d_ws, size_t ws_size,
                              hipStream_t stream) {
    (void)in_sizes; (void)n_in; (void)out_size; (void)ws_size;
    const float* x    = (const float*)d_in[0];
    const int*   pid  = (const int*)  d_in[1];
    const float* cosb = (const float*)d_in[2];
    const float* sinb = (const float*)d_in[3];
    const float* rq   = (const float*)d_in[4];
    const float* rk   = (const float*)d_in[5];
    const float* rv   = (const float*)d_in[6];
    const float* qw1  = (const float*)d_in[7];
    const float* qw2  = (const float*)d_in[8];
    const float* kw1  = (const float*)d_in[9];
    const float* kw2  = (const float*)d_in[10];
    const float* vw1  = (const float*)d_in[11];
    const float* vw2  = (const float*)d_in[12];
    const float* ow   = (const float*)d_in[13];
    float* out = (float*)d_out;

    const size_t MB = 1u << 20;
    char* wsb = (char*)d_ws;
    u16* qb   = (u16*)(wsb + 0 * MB);      // 8 MB  bf16 [B,H,T,D]
    u16* kb   = (u16*)(wsb + 8 * MB);      // 8 MB
    u16* vb   = (u16*)(wsb + 16 * MB);     // 8 MB
    u16* aobf = (u16*)(wsb + 24 * MB);     // 8 MB  bf16 [B,T,C]
    u16* owbf = (u16*)(wsb + 32 * MB);     // 2 MB  bf16 o_w
    unsigned int* idxbuf = (unsigned int*)(wsb + 34 * MB);       // 6 MB
    float2*       wtbuf  = (float2*)(wsb + 41 * MB);             // 12 MB
    unsigned int* counts = (unsigned int*)(wsb + 54 * MB);       // 768 B

    hipMemsetAsync(counts, 0, 1024, stream);

    hipLaunchKernelGGL(router_kernel, dim3(256), dim3(256), 0, stream,
                       x, rq, rk, rv, counts, idxbuf, wtbuf);
    hipLaunchKernelGGL(cvt_bf16_kernel, dim3(1024), dim3(256), 0, stream,
                       ow, owbf, 1024 * 1024 / 4);
    hipLaunchKernelGGL(expert_kernel, dim3(84 * CH), dim3(512), 0, stream,
                       x, pid, cosb, sinb, qw1, qw2, kw1, kw2, vw1, vw2,
                       counts, idxbuf, wtbuf, qb, kb, vb);
    hipLaunchKernelGGL(attn_kernel, dim3(1024), dim3(256), 0, stream,
                       qb, kb, vb, aobf);
    hipLaunchKernelGGL(oproj_kernel, dim3(256), dim3(256), 0, stream,
                       aobf, owbf, out);
}

// Round 7
// 271.100 us; speedup vs baseline: 4.8012x; 1.0912x over previous
//
#include <hip/hip_runtime.h>
#include <math.h>

#define BB 4
#define TT 1024
#define CCH 1024
#define HH 16
#define DD 64
#define EE 8
#define HID 128
#define CAP 8192    // entries per (proj,pair) list; mean is 65536/28 ~= 2340
#define CH 3        // chunk-blocks per (proj,pair) list

typedef unsigned short u16;
typedef short bf16x8 __attribute__((ext_vector_type(8)));
typedef float f32x4 __attribute__((ext_vector_type(4)));

__device__ __forceinline__ u16 f2bf(float f) {
    unsigned int u = __float_as_uint(f);
    unsigned int r = (u + 0x7FFFu + ((u >> 16) & 1u)) >> 16;   // RNE
    return (u16)r;
}

// ============================================================================
// Kernel 1: router. One thread per token-head g = (b*T+t)*16+h; fp32-exact
// top-2 of 8. Tokens binned by (proj, expert-PAIR): pe = p*64 + lo*8 + hi.
// ============================================================================
__global__ __launch_bounds__(256) void router_kernel(
    const float* __restrict__ x,
    const float* __restrict__ rq, const float* __restrict__ rk, const float* __restrict__ rv,
    unsigned int* __restrict__ counts,
    unsigned int* __restrict__ idxbuf, float2* __restrict__ wtbuf)
{
    const int tid = threadIdx.x;
    const unsigned int g = blockIdx.x * 256 + tid;

    __shared__ float rS[3][64][8];
    __shared__ int lcnt[192];
    __shared__ int lbase[192];

    for (int i = tid; i < 1536; i += 256) {
        int p = i >> 9, rem = i & 511;
        const float* rp = (p == 0) ? rq : (p == 1) ? rk : rv;
        rS[p][rem >> 3][rem & 7] = rp[rem];
    }
    if (tid < 192) lcnt[tid] = 0;
    __syncthreads();

    float lg[3][8];
    #pragma unroll
    for (int p = 0; p < 3; ++p)
        #pragma unroll
        for (int e = 0; e < 8; ++e) lg[p][e] = 0.f;

    const float* xr = x + (size_t)g * 64;
    for (int i4 = 0; i4 < 16; ++i4) {
        float4 xv = ((const float4*)xr)[i4];
        float xa[4] = {xv.x, xv.y, xv.z, xv.w};
        #pragma unroll
        for (int m = 0; m < 4; ++m) {
            int d = i4 * 4 + m;
            #pragma unroll
            for (int p = 0; p < 3; ++p) {
                float4 r0 = *(const float4*)&rS[p][d][0];
                float4 r1 = *(const float4*)&rS[p][d][4];
                lg[p][0] += xa[m] * r0.x; lg[p][1] += xa[m] * r0.y;
                lg[p][2] += xa[m] * r0.z; lg[p][3] += xa[m] * r0.w;
                lg[p][4] += xa[m] * r1.x; lg[p][5] += xa[m] * r1.y;
                lg[p][6] += xa[m] * r1.z; lg[p][7] += xa[m] * r1.w;
            }
        }
    }

    int ppe[3]; float2 pw[3]; int slot[3];
    #pragma unroll
    for (int p = 0; p < 3; ++p) {
        int i1 = 0; float v1 = lg[p][0];
        #pragma unroll
        for (int e = 1; e < 8; ++e) { if (lg[p][e] > v1) { v1 = lg[p][e]; i1 = e; } }
        int i2 = -1; float v2 = -3.402823466e38f;
        #pragma unroll
        for (int e = 0; e < 8; ++e) { if (e != i1 && lg[p][e] > v2) { v2 = lg[p][e]; i2 = e; } }
        float z = __expf(v2 - v1);
        float inv = 1.f / (1.f + z);
        float wa = inv, wb = z * inv;
        int lo = min(i1, i2), hi = max(i1, i2);
        float wlo = (i1 < i2) ? wa : wb;
        float whi = (i1 < i2) ? wb : wa;
        int pel = p * 64 + lo * 8 + hi;
        ppe[p] = pel; pw[p] = make_float2(wlo, whi);
        slot[p] = atomicAdd(&lcnt[pel], 1);
    }
    __syncthreads();
    if (tid < 192) {
        int c = lcnt[tid];
        lbase[tid] = c ? (int)atomicAdd(&counts[tid], (unsigned int)c) : 0;
    }
    __syncthreads();
    #pragma unroll
    for (int p = 0; p < 3; ++p) {
        int pos = lbase[ppe[p]] + slot[p];
        if (pos < CAP) {
            idxbuf[ppe[p] * CAP + pos] = g;
            wtbuf[ppe[p] * CAP + pos]  = pw[p];
        }
    }
}

// ============================================================================
// Kernel 2: pair-grouped expert MLP, bf16 MFMA, wave-independent.
// Block = one of 84 (proj,pair) x CH chunks, 768 threads = 12 waves
// (3 waves/SIMD; ~168 VGPR cap so no spills; LDS 87 KB -> 1 block/CU).
// Semantics identical to the PASSING R4 kernel; only wave count changed.
// ============================================================================
__global__ __launch_bounds__(768) void expert_kernel(
    const float* __restrict__ x, const int* __restrict__ pos_ids,
    const float* __restrict__ cosb, const float* __restrict__ sinb,
    const float* __restrict__ w1q, const float* __restrict__ w2q,
    const float* __restrict__ w1k, const float* __restrict__ w2k,
    const float* __restrict__ w1v, const float* __restrict__ w2v,
    const unsigned int* __restrict__ counts,
    const unsigned int* __restrict__ idxbuf, const float2* __restrict__ wtbuf,
    u16* __restrict__ qb, u16* __restrict__ kb, u16* __restrict__ vb)
{
    const int tid = threadIdx.x;
    const int pe84 = blockIdx.x / CH, chunk = blockIdx.x - pe84 * CH;
    const int p = pe84 / 28;
    int q28 = pe84 - p * 28;
    int lo = 0;
    while (q28 >= 7 - lo) { q28 -= 7 - lo; ++lo; }
    const int hi = lo + 1 + q28;
    const int pe = p * 64 + lo * 8 + hi;

    int n = (int)counts[pe]; if (n == 0) return; if (n > CAP) n = CAP;

    const float* w1base = (p == 0) ? w1q : (p == 1) ? w1k : w1v;
    const float* w2base = (p == 0) ? w2q : (p == 1) ? w2k : w2v;
    u16* outp = (p == 0) ? qb : (p == 1) ? kb : vb;
    const unsigned int* il = idxbuf + pe * CAP;
    const float2* wl = wtbuf + pe * CAP;

    __shared__ u16 w1t[2][128][72];    // [e][f][d]  B-operand GEMM1   36.9 KB
    __shared__ u16 w2t[2][64][136];    // [e][g][f]  B-operand GEMM2   34.8 KB
    __shared__ u16 hsw[12][16][40];    // per-wave gelu scratch        15.4 KB

    // ---- stage both experts' weights, bf16-transposed (once) ----
    #pragma unroll
    for (int e = 0; e < 2; ++e) {
        int ex = e ? hi : lo;
        const float* w1 = w1base + ex * 64 * 128;   // [d][f]
        const float* w2 = w2base + ex * 128 * 64;   // [f][g]
        for (int i = tid; i < 8192; i += 768)
            w1t[e][i & 127][i >> 7] = f2bf(w1[i]);
        for (int i = tid; i < 8192; i += 768)
            w2t[e][i & 63][i >> 6] = f2bf(w2[i]);
    }
    __syncthreads();

    const int lane = tid & 63, w = tid >> 6, quad = lane >> 4, m16 = lane & 15;
    const int wid = chunk * 12 + w;
    const int WRK = CH * 12;
    const int nsub = (n + 15) >> 4;

    for (int s = wid; s < nsub; s += WRK) {
        const int base = s * 16;
        // ---- lane 0..15: per-token metadata; broadcast via shfl ----
        unsigned int gtok = 0, obase = 0; float wlo_ = 0.f, whi_ = 0.f;
        int posv = 0, valid = 0;
        if (lane < 16) {
            int j = base + lane;
            valid = (j < n);
            int jc = valid ? j : (n - 1);
            gtok = il[jc];
            float2 wv = wl[jc];
            wlo_ = valid ? wv.x : 0.f; whi_ = valid ? wv.y : 0.f;
            unsigned int b_ = gtok >> 14, h_ = gtok & 15, t_ = (gtok >> 4) & 1023;
            obase = ((b_ * 16 + h_) * 1024 + t_) * 64;
            posv = pos_ids[b_ * 1024 + t_];
        }
        unsigned int gm = (unsigned int)__shfl((int)gtok, m16, 64);

        // ---- A-frags: x[tok][8q..8q+8) and x[tok][32+8q..) from global ----
        const float* xr = x + (size_t)gm * 64 + 8 * quad;
        float4 xa0 = *(const float4*)(xr);
        float4 xa1 = *(const float4*)(xr + 4);
        float4 xb0 = *(const float4*)(xr + 32);
        float4 xb1 = *(const float4*)(xr + 36);
        bf16x8 A0, A1;
        A0[0] = (short)f2bf(xa0.x); A0[1] = (short)f2bf(xa0.y);
        A0[2] = (short)f2bf(xa0.z); A0[3] = (short)f2bf(xa0.w);
        A0[4] = (short)f2bf(xa1.x); A0[5] = (short)f2bf(xa1.y);
        A0[6] = (short)f2bf(xa1.z); A0[7] = (short)f2bf(xa1.w);
        A1[0] = (short)f2bf(xb0.x); A1[1] = (short)f2bf(xb0.y);
        A1[2] = (short)f2bf(xb0.z); A1[3] = (short)f2bf(xb0.w);
        A1[4] = (short)f2bf(xb1.x); A1[5] = (short)f2bf(xb1.y);
        A1[6] = (short)f2bf(xb1.z); A1[7] = (short)f2bf(xb1.w);

        f32x4 acc2[2][4];
        #pragma unroll
        for (int e = 0; e < 2; ++e)
            #pragma unroll
            for (int nt = 0; nt < 4; ++nt) acc2[e][nt] = (f32x4){0.f, 0.f, 0.f, 0.f};

        #pragma unroll
        for (int e = 0; e < 2; ++e) {
            #pragma unroll
            for (int kk = 0; kk < 4; ++kk) {
                // --- GEMM1 for 32 hidden features (n-tiles 2kk, 2kk+1) ---
                int nt0 = 2 * kk, nt1 = 2 * kk + 1;
                bf16x8 b0a = *(const bf16x8*)&w1t[e][16 * nt0 + m16][8 * quad];
                bf16x8 b0b = *(const bf16x8*)&w1t[e][16 * nt0 + m16][32 + 8 * quad];
                bf16x8 b1a = *(const bf16x8*)&w1t[e][16 * nt1 + m16][8 * quad];
                bf16x8 b1b = *(const bf16x8*)&w1t[e][16 * nt1 + m16][32 + 8 * quad];
                f32x4 c0 = (f32x4){0.f, 0.f, 0.f, 0.f};
                f32x4 c1 = (f32x4){0.f, 0.f, 0.f, 0.f};
                c0 = __builtin_amdgcn_mfma_f32_16x16x32_bf16(A0, b0a, c0, 0, 0, 0);
                c0 = __builtin_amdgcn_mfma_f32_16x16x32_bf16(A1, b0b, c0, 0, 0, 0);
                c1 = __builtin_amdgcn_mfma_f32_16x16x32_bf16(A0, b1a, c1, 0, 0, 0);
                c1 = __builtin_amdgcn_mfma_f32_16x16x32_bf16(A1, b1b, c1, 0, 0, 0);
                // --- gelu -> per-wave scratch (C-layout -> A-layout) ---
                #pragma unroll
                for (int r = 0; r < 4; ++r) {
                    float z = c0[r];
                    float u = 1.5957691216057308f * (z + 0.044715f * z * z * z);
                    hsw[w][4 * quad + r][m16] = f2bf(z / (1.f + __expf(-u)));
                    float z2 = c1[r];
                    float u2 = 1.5957691216057308f * (z2 + 0.044715f * z2 * z2 * z2);
                    hsw[w][4 * quad + r][16 + m16] = f2bf(z2 / (1.f + __expf(-u2)));
                }
                bf16x8 A2 = *(const bf16x8*)&hsw[w][m16][8 * quad];
                // --- GEMM2 partial: acc += A2 x w2[32kk..32kk+32) ---
                #pragma unroll
                for (int nt2 = 0; nt2 < 4; ++nt2) {
                    bf16x8 b2 = *(const bf16x8*)&w2t[e][16 * nt2 + m16][32 * kk + 8 * quad];
                    acc2[e][nt2] = __builtin_amdgcn_mfma_f32_16x16x32_bf16(A2, b2, acc2[e][nt2], 0, 0, 0);
                }
            }
        }

        // ---- combine experts + RoPE + store (C rows = tokens 4q+r) ----
        #pragma unroll
        for (int r = 0; r < 4; ++r) {
            int row = 4 * quad + r;
            float wlo_r = __shfl(wlo_, row, 64);
            float whi_r = __shfl(whi_, row, 64);
            int   pos_r = __shfl(posv, row, 64);
            unsigned int ob = (unsigned int)__shfl((int)obase, row, 64);
            int   val_r = __shfl(valid, row, 64);
            if (p < 2) {
                #pragma unroll
                for (int ntp = 0; ntp < 2; ++ntp) {
                    int d = 16 * ntp + m16;
                    float v1 = wlo_r * acc2[0][ntp][r]     + whi_r * acc2[1][ntp][r];
                    float v2 = wlo_r * acc2[0][ntp + 2][r] + whi_r * acc2[1][ntp + 2][r];
                    float cd = cosb[pos_r * 64 + d];
                    float sd = sinb[pos_r * 64 + d];
                    if (val_r) {
                        outp[ob + d]      = f2bf(v1 * cd - v2 * sd);
                        outp[ob + d + 32] = f2bf(v2 * cd + v1 * sd);
                    }
                }
            } else {
                #pragma unroll
                for (int nt = 0; nt < 4; ++nt) {
                    float v = wlo_r * acc2[0][nt][r] + whi_r * acc2[1][nt][r];
                    if (val_r) outp[ob + 16 * nt + m16] = f2bf(v);
                }
            }
        }
    }
}

// ============================================================================
// Kernel 3: fp32 -> bf16 convert (for o_w)
// ============================================================================
__global__ __launch_bounds__(256) void cvt_bf16_kernel(
    const float* __restrict__ in, u16* __restrict__ out, int n4)
{
    int i = blockIdx.x * 256 + threadIdx.x;
    if (i >= n4) return;
    float4 v = ((const float4*)in)[i];
    unsigned int lov = (unsigned int)f2bf(v.x) | ((unsigned int)f2bf(v.y) << 16);
    unsigned int hiv = (unsigned int)f2bf(v.z) | ((unsigned int)f2bf(v.w) << 16);
    ((uint2*)out)[i] = make_uint2(lov, hiv);
}

// ============================================================================
// Kernel 4: flash attention, bf16 MFMA, R4 numerics (running-max online
// softmax, 0.125 scale applied here). Structure: block = paired q-tiles
// (i, 15-i) of one (b,h) plane -> uniform 17 k-tiles/block; Q A-frags
// loaded directly from global (addressing identical to R4's LDS path).
// ============================================================================
__global__ __launch_bounds__(256) void attn_kernel(
    const u16* __restrict__ qbp, const u16* __restrict__ kbp,
    const u16* __restrict__ vbp, u16* __restrict__ ao)
{
    const int tid = threadIdx.x;
    const int i8 = blockIdx.x & 7;
    const int plane_i = blockIdx.x >> 3;           // 64 planes
    const int h = plane_i & 15, b = plane_i >> 4;
    const size_t plane = (size_t)plane_i * 1024 * 64;
    const u16* qp = qbp + plane;
    const u16* kp = kbp + plane;
    const u16* vp = vbp + plane;

    const int w = tid >> 6, lane = tid & 63, quad = lane >> 4, m16 = lane & 15;

    __shared__ u16 Ks[64][72];
    __shared__ u16 Vt[64][72];        // [d][kj]
    __shared__ u16 Ps[4][16][72];     // per-wave P scratch

    #pragma unroll 1
    for (int half = 0; half < 2; ++half) {
        const int qt = half ? (15 - i8) : i8;
        const int q0 = qt * 64;

        // Q A-frags straight from global (row 16w+m16, k = 8*quad [+32])
        const u16* qrow = &qp[(size_t)(q0 + 16 * w + m16) * 64 + 8 * quad];
        bf16x8 aq0 = *(const bf16x8*)(qrow);
        bf16x8 aq1 = *(const bf16x8*)(qrow + 32);

        float m_r[4], l_r[4];
        #pragma unroll
        for (int i = 0; i < 4; ++i) { m_r[i] = -1e30f; l_r[i] = 0.f; }
        f32x4 oacc[4];
        #pragma unroll
        for (int i = 0; i < 4; ++i) oacc[i] = (f32x4){0.f, 0.f, 0.f, 0.f};

        for (int kt = 0; kt <= qt; ++kt) {
            const int k0 = kt * 64;
            __syncthreads();
            {
                int row = tid >> 2, seg = tid & 3;
                const uint4* src = (const uint4*)&kp[(size_t)(k0 + row) * 64 + seg * 16];
                uint4 v0 = src[0], v1 = src[1];
                uint4* dst = (uint4*)&Ks[row][seg * 16];
                dst[0] = v0; dst[1] = v1;
            }
            {
                int kj = tid & 63, dg = tid >> 6;
                #pragma unroll
                for (int pp = 0; pp < 4; ++pp) {
                    int d0 = dg * 4 + pp * 16;
                    ushort4 v = *(const ushort4*)&vp[(size_t)(k0 + kj) * 64 + d0];
                    Vt[d0 + 0][kj] = v.x; Vt[d0 + 1][kj] = v.y;
                    Vt[d0 + 2][kj] = v.z; Vt[d0 + 3][kj] = v.w;
                }
            }
            __syncthreads();

            // S = Q K^T
            f32x4 sv[4];
            #pragma unroll
            for (int ct = 0; ct < 4; ++ct) {
                bf16x8 bk0 = *(const bf16x8*)&Ks[16 * ct + m16][8 * quad];
                bf16x8 bk1 = *(const bf16x8*)&Ks[16 * ct + m16][32 + 8 * quad];
                f32x4 acc = (f32x4){0.f, 0.f, 0.f, 0.f};
                acc = __builtin_amdgcn_mfma_f32_16x16x32_bf16(aq0, bk0, acc, 0, 0, 0);
                acc = __builtin_amdgcn_mfma_f32_16x16x32_bf16(aq1, bk1, acc, 0, 0, 0);
                sv[ct] = acc;
            }

            // scale + causal mask (C layout: row = 4*quad+reg, col = 16*ct+m16)
            float s[4][4];
            const bool diag = (kt == qt);
            #pragma unroll
            for (int ct = 0; ct < 4; ++ct)
                #pragma unroll
                for (int reg = 0; reg < 4; ++reg) {
                    float v = sv[ct][reg] * 0.125f;
                    if (diag) {
                        int col = 16 * ct + m16;
                        int row = 16 * w + 4 * quad + reg;
                        if (col > row) v = -1e30f;
                    }
                    s[ct][reg] = v;
                }

            // online softmax (R4 numerics): running max + rescale
            float nm[4], al[4];
            #pragma unroll
            for (int reg = 0; reg < 4; ++reg) {
                float rm = fmaxf(fmaxf(s[0][reg], s[1][reg]), fmaxf(s[2][reg], s[3][reg]));
                #pragma unroll
                for (int off = 1; off < 16; off <<= 1) rm = fmaxf(rm, __shfl_xor(rm, off, 16));
                float mn = fmaxf(m_r[reg], rm);
                nm[reg] = mn;
                al[reg] = __expf(m_r[reg] - mn);
            }
            #pragma unroll
            for (int reg = 0; reg < 4; ++reg) {
                float sum = 0.f;
                #pragma unroll
                for (int ct = 0; ct < 4; ++ct) {
                    float pv = __expf(s[ct][reg] - nm[reg]);
                    s[ct][reg] = pv;
                    sum += pv;
                }
                #pragma unroll
                for (int off = 1; off < 16; off <<= 1) sum += __shfl_xor(sum, off, 16);
                l_r[reg] = l_r[reg] * al[reg] + sum;
                m_r[reg] = nm[reg];
            }

            // P: C-layout -> A-layout via per-wave LDS (in-wave ordering)
            #pragma unroll
            for (int ct = 0; ct < 4; ++ct)
                #pragma unroll
                for (int reg = 0; reg < 4; ++reg)
                    Ps[w][4 * quad + reg][16 * ct + m16] = f2bf(s[ct][reg]);

            #pragma unroll
            for (int dt = 0; dt < 4; ++dt)
                #pragma unroll
                for (int reg = 0; reg < 4; ++reg) oacc[dt][reg] *= al[reg];

            bf16x8 ap0 = *(const bf16x8*)&Ps[w][m16][8 * quad];
            bf16x8 ap1 = *(const bf16x8*)&Ps[w][m16][32 + 8 * quad];
            #pragma unroll
            for (int dt = 0; dt < 4; ++dt) {
                bf16x8 bv0 = *(const bf16x8*)&Vt[16 * dt + m16][8 * quad];
                bf16x8 bv1 = *(const bf16x8*)&Vt[16 * dt + m16][32 + 8 * quad];
                oacc[dt] = __builtin_amdgcn_mfma_f32_16x16x32_bf16(ap0, bv0, oacc[dt], 0, 0, 0);
                oacc[dt] = __builtin_amdgcn_mfma_f32_16x16x32_bf16(ap1, bv1, oacc[dt], 0, 0, 0);
            }
        }

        #pragma unroll
        for (int reg = 0; reg < 4; ++reg) {
            float linv = 1.f / l_r[reg];
            int row = q0 + 16 * w + 4 * quad + reg;
            size_t base = ((size_t)(b * 1024) + row) * 1024 + h * 64;
            #pragma unroll
            for (int dt = 0; dt < 4; ++dt)
                ao[base + 16 * dt + m16] = f2bf(oacc[dt][reg] * linv);
        }
    }
}

// ============================================================================
// Kernel 5: output projection, bf16 MFMA gemm_bt. 128x128 tile, BK=32
// (R4-verbatim, known good).
// ============================================================================
__global__ __launch_bounds__(256) void oproj_kernel(
    const u16* __restrict__ A, const u16* __restrict__ Bw,
    float* __restrict__ out)
{
    const int tid = threadIdx.x;
    const int bn = blockIdx.x & 7;
    const int bm = blockIdx.x >> 3;
    const int m0 = bm * 128, n0 = bn * 128;
    const int w = tid >> 6, lane = tid & 63, quad = lane >> 4, m16 = lane & 15;
    const int wm = (w >> 1) * 64, wn = (w & 1) * 64;

    __shared__ u16 As[128][32];
    __shared__ u16 Bs[128][32];

    f32x4 acc[4][4];
    #pragma unroll
    for (int mt = 0; mt < 4; ++mt)
        #pragma unroll
        for (int nt = 0; nt < 4; ++nt) acc[mt][nt] = (f32x4){0.f, 0.f, 0.f, 0.f};

    for (int k0 = 0; k0 < 1024; k0 += 32) {
        __syncthreads();
        {
            int row = tid >> 1, sg = (tid & 1) * 16;
            const uint4* srcA = (const uint4*)&A[(size_t)(m0 + row) * 1024 + k0 + sg];
            uint4 a0 = srcA[0], a1 = srcA[1];
            uint4* dstA = (uint4*)&As[row][sg];
            dstA[0] = a0; dstA[1] = a1;
            const uint4* srcB = (const uint4*)&Bw[(size_t)(n0 + row) * 1024 + k0 + sg];
            uint4 b0 = srcB[0], b1 = srcB[1];
            uint4* dstB = (uint4*)&Bs[row][sg];
            dstB[0] = b0; dstB[1] = b1;
        }
        __syncthreads();
        bf16x8 af[4], bf_[4];
        #pragma unroll
        for (int mt = 0; mt < 4; ++mt) af[mt] = *(const bf16x8*)&As[wm + 16 * mt + m16][8 * quad];
        #pragma unroll
        for (int nt = 0; nt < 4; ++nt) bf_[nt] = *(const bf16x8*)&Bs[wn + 16 * nt + m16][8 * quad];
        #pragma unroll
        for (int mt = 0; mt < 4; ++mt)
            #pragma unroll
            for (int nt = 0; nt < 4; ++nt)
                acc[mt][nt] = __builtin_amdgcn_mfma_f32_16x16x32_bf16(af[mt], bf_[nt], acc[mt][nt], 0, 0, 0);
    }
    #pragma unroll
    for (int mt = 0; mt < 4; ++mt)
        #pragma unroll
        for (int nt = 0; nt < 4; ++nt)
            #pragma unroll
            for (int reg = 0; reg < 4; ++reg)
                out[(size_t)(m0 + wm + 16 * mt + 4 * quad + reg) * 1024 + n0 + wn + 16 * nt + m16] =
                    acc[mt][nt][reg];
}

// ============================================================================
extern "C" void kernel_launch(void* const* d_in, const int* in_sizes, int n_in,
                              void* d_out, int out_size, void* d_ws, size_t ws_size,
                              hipStream_t stream) {
    (void)in_sizes; (void)n_in; (void)out_size; (void)ws_size;
    const float* x    = (const float*)d_in[0];
    const int*   pid  = (const int*)  d_in[1];
    const float* cosb = (const float*)d_in[2];
    const float* sinb = (const float*)d_in[3];
    const float* rq   = (const float*)d_in[4];
    const float* rk   = (const float*)d_in[5];
    const float* rv   = (const float*)d_in[6];
    const float* qw1  = (const float*)d_in[7];
    const float* qw2  = (const float*)d_in[8];
    const float* kw1  = (const float*)d_in[9];
    const float* kw2  = (const float*)d_in[10];
    const float* vw1  = (const float*)d_in[11];
    const float* vw2  = (const float*)d_in[12];
    const float* ow   = (const float*)d_in[13];
    float* out = (float*)d_out;

    const size_t MB = 1u << 20;
    char* wsb = (char*)d_ws;
    u16* qb   = (u16*)(wsb + 0 * MB);      // 8 MB  bf16 [B,H,T,D]
    u16* kb   = (u16*)(wsb + 8 * MB);      // 8 MB
    u16* vb   = (u16*)(wsb + 16 * MB);     // 8 MB
    u16* aobf = (u16*)(wsb + 24 * MB);     // 8 MB  bf16 [B,T,C]
    u16* owbf = (u16*)(wsb + 32 * MB);     // 2 MB  bf16 o_w
    unsigned int* idxbuf = (unsigned int*)(wsb + 34 * MB);       // 6 MB
    float2*       wtbuf  = (float2*)(wsb + 41 * MB);             // 12 MB
    unsigned int* counts = (unsigned int*)(wsb + 54 * MB);       // 768 B

    hipMemsetAsync(counts, 0, 1024, stream);

    hipLaunchKernelGGL(router_kernel, dim3(256), dim3(256), 0, stream,
                       x, rq, rk, rv, counts, idxbuf, wtbuf);
    hipLaunchKernelGGL(cvt_bf16_kernel, dim3(1024), dim3(256), 0, stream,
                       ow, owbf, 1024 * 1024 / 4);
    hipLaunchKernelGGL(expert_kernel, dim3(84 * CH), dim3(768), 0, stream,
                       x, pid, cosb, sinb, qw1, qw2, kw1, kw2, vw1, vw2,
                       counts, idxbuf, wtbuf, qb, kb, vb);
    hipLaunchKernelGGL(attn_kernel, dim3(512), dim3(256), 0, stream,
                       qb, kb, vb, aobf);
    hipLaunchKernelGGL(oproj_kernel, dim3(256), dim3(256), 0, stream,
                       aobf, owbf, out);
}